// Round 10
// baseline (788.732 us; speedup 1.0000x reference)
//
#include <hip/hip_runtime.h>
#include <hip/hip_bf16.h>
#include <cstddef>

#define BSZ 16
#define NPT 1024
#define KNN 30
#define TKR 9
#define FLT_BIG 3.402823466e+38f

typedef unsigned short u16;
typedef __attribute__((ext_vector_type(8))) u16 u16x8;
typedef __attribute__((ext_vector_type(4))) float f32x4;

__device__ __forceinline__ float gelu_f(float x) {
    return 0.5f * x * (1.0f + erff(x * 0.7071067811865476f));
}

__device__ __forceinline__ u16 bf16_rne(float a) {
    unsigned u = __float_as_uint(a);
    u += 0x7FFFu + ((u >> 16) & 1u);
    return (u16)(u >> 16);
}
__device__ __forceinline__ float bf16_tof(u16 h) {
    return __uint_as_float(((unsigned)h) << 16);
}
__device__ __forceinline__ void split_bf16(float a, u16& h, u16& l) {
    h = bf16_rne(a);
    float r = a - bf16_tof(h);
    l = bf16_rne(r);
}

// Packed MFMA operand layout (R16): element (row, k) of a [Rows][K] operand
// lives at u16 offset  T*4096 + kc*1024 + (row&127)*8 + (k&7),
// where T = (k>>5)*(Rows>>7) + (row>>7), kc = (k>>3)&3.
// Each (k-panel, row-panel) tile is a contiguous 8KB block == LDS image.
__device__ __forceinline__ size_t pack_off(int row, int k, int npanels_row) {
    return (size_t)((k >> 5) * npanels_row + (row >> 7)) * 4096
         + (size_t)(((k >> 3) & 3) * 1024 + (row & 127) * 8 + (k & 7));
}

// ---------------------------------------------------------------------------
// 1. prep_all: layer 0 = transpose x; layers 1..3 = WZ_l = [W;S;pad] (f32);
//    layer 4 = bf16 split weights w4t{H,L}, tile-packed (Rows=256, K=1280).
// ---------------------------------------------------------------------------
__global__ __launch_bounds__(256) void prep_all(
    const float* __restrict__ x, float* __restrict__ pts,
    const float* __restrict__ W1, const float* __restrict__ S1, float* __restrict__ wz1,
    const float* __restrict__ W2, const float* __restrict__ S2, float* __restrict__ wz2,
    const float* __restrict__ W3, const float* __restrict__ S3, float* __restrict__ wz3,
    const float* __restrict__ W4, const float* __restrict__ S4,
    u16* __restrict__ w4tH, u16* __restrict__ w4tL) {
    int layer = blockIdx.y;
    int t = blockIdx.x * 256 + threadIdx.x;
    if (layer == 0) {
        if (t >= BSZ * NPT) return;
        int b = t >> 10, n = t & 1023;
        const float* xp = x + (size_t)b * 3 * NPT;
        pts[t * 3 + 0] = xp[n];
        pts[t * 3 + 1] = xp[NPT + n];
        pts[t * 3 + 2] = xp[2 * NPT + n];
        return;
    }
    if (layer == 4) {
        // W4:[1152][256], S4:[128][256] -> packed w4t{H,L}, row=n in [0,256)
        if (t >= 1280 * 256) return;
        int k = t >> 8, n = t & 255;
        float v = (k < 1152) ? W4[(size_t)k * 256 + n] : S4[(size_t)(k - 1152) * 256 + n];
        u16 h, l;
        split_bf16(v, h, l);
        size_t off = pack_off(n, k, 2);
        w4tH[off] = h;
        w4tL[off] = l;
        return;
    }
    const float *W, *S; float* WZ; int KW, KS, N, kpad;
    if (layer == 1)      { W = W1; S = S1; WZ = wz1; KW = 27;   KS = 3;   N = 64;  kpad = 32;  }
    else if (layer == 2) { W = W2; S = S2; WZ = wz2; KW = 576;  KS = 64;  N = 64;  kpad = 640; }
    else                 { W = W3; S = S3; WZ = wz3; KW = 576;  KS = 64;  N = 128; kpad = 640; }
    if (t >= kpad * N) return;
    int k = t / N, n = t - k * N;
    float v = 0.0f;
    if (k < KW) v = W[(size_t)k * N + n];
    else if (k < KW + KS) v = S[(size_t)(k - KW) * N + n];
    WZ[t] = v;
}

// ---------------------------------------------------------------------------
// 2. FUSED kNN + basis. R20: selection via u32 shfl_xor butterfly max
//    + ballot/ctz argmax + one shfl j-broadcast. Tie semantics ==
//    reference top_k (value desc, lower index first).
// ---------------------------------------------------------------------------
__global__ __launch_bounds__(256) void knn_basis_kernel(
    const float* __restrict__ pts, const float* __restrict__ B_ff,
    const float* __restrict__ mlp_W, const float* __restrict__ permx,
    int* __restrict__ idx, float* __restrict__ P) {
    __shared__ float npt[4][KNN * 3];
    __shared__ float feats[4][7 * KNN];
    __shared__ float sc[4][64];
    __shared__ float zl[4][16];
    __shared__ float w[4][16];
    __shared__ float sZs[4][16];
    __shared__ float sCs[4][16];
    __shared__ int sIds[4][KNN];
    int tid = threadIdx.x;
    int wave = tid >> 6, lane = tid & 63;
    int bn_ = blockIdx.x * 4 + wave;
    int b = bn_ >> 10;

    // ---- kNN phase ----
    {
        double px = (double)pts[(size_t)bn_ * 3 + 0];
        double py = (double)pts[(size_t)bn_ * 3 + 1];
        double pz = (double)pts[(size_t)bn_ * 3 + 2];
        double xn = px * px + py * py + pz * pz;
        const float* pb = pts + (size_t)(b << 10) * 3;
        int base = lane * 16;
        unsigned mono[16];
        #pragma unroll
        for (int j = 0; j < 16; j++) {
            int m = base + j;
            double qx = (double)pb[m * 3 + 0];
            double qy = (double)pb[m * 3 + 1];
            double qz = (double)pb[m * 3 + 2];
            double inner = px * qx + py * qy + pz * qz;
            double xm = qx * qx + qy * qy + qz * qz;
            double cd = 2.0 * inner - xn - xm;          // exact ordering source
            float cf = (float)cd;                        // correctly-rounded f32
            unsigned bb = __float_as_uint(cf);
            mono[j] = (bb & 0x80000000u) ? ~bb : (bb | 0x80000000u);
        }
        unsigned alive = 0xFFFFu;
        unsigned c1v = 0u, c2v = 0u;
        int c1j = 0, c2j = 0;
        #pragma unroll
        for (int j = 0; j < 16; j++) {
            unsigned v = mono[j];
            if (v > c1v) { c2v = c1v; c2j = c1j; c1v = v; c1j = j; }
            else if (v > c2v) { c2v = v; c2j = j; }
        }
        bool have2 = true;
        for (int it = 0; it < KNN; it++) {
            unsigned m = c1v;
            #pragma unroll
            for (int s = 1; s < 64; s <<= 1) {
                unsigned ov = (unsigned)__shfl_xor((int)m, s, 64);
                m = (ov > m) ? ov : m;
            }
            unsigned long long ball = __ballot(c1v == m);
            int wlan = (int)__builtin_ctzll(ball);    // lowest lane = lowest idx
            int jw = __shfl(c1j, wlan, 64);
            int bi = (wlan << 4) + jw;
            if (lane == it) sIds[wave][it] = bi;
            if (lane == wlan) {
                alive &= ~(1u << c1j);
                if (have2) {
                    c1v = c2v; c1j = c2j; have2 = false;
                } else {
                    unsigned a1 = 0u, a2 = 0u;
                    int j1 = 0, j2 = 0;
                    #pragma unroll
                    for (int j = 0; j < 16; j++) {
                        unsigned v = ((alive >> j) & 1u) ? mono[j] : 0u;
                        if (v > a1) { a2 = a1; j2 = j1; a1 = v; j1 = j; }
                        else if (v > a2) { a2 = v; j2 = j; }
                    }
                    c1v = a1; c1j = j1; c2v = a2; c2j = j2;
                    have2 = true;
                }
            }
        }
        __builtin_amdgcn_wave_barrier();
        if (lane < KNN) idx[(size_t)bn_ * KNN + lane] = sIds[wave][lane];
    }
    __syncthreads();

    // ---- basis phase ----
    if (lane < KNN) {
        int m = sIds[wave][lane];
        const float* q = pts + ((size_t)(b << 10) + m) * 3;
        npt[wave][lane * 3 + 0] = q[0];
        npt[wave][lane * 3 + 1] = q[1];
        npt[wave][lane * 3 + 2] = q[2];
    }
    __syncthreads();
    if (lane < KNN) {
        float sx = npt[wave][0], sy = npt[wave][1], sz = npt[wave][2];
        float rx = npt[wave][lane * 3 + 0] - sx;
        float ry = npt[wave][lane * 3 + 1] - sy;
        float rz = npt[wave][lane * 3 + 2] - sz;
        float sq = rx * rx + ry * ry + rz * rz;
        float dist = (sq > 0.0f) ? sqrtf(sq) : 0.0f;
        feats[wave][lane * 7 + 0] = sx;
        feats[wave][lane * 7 + 1] = sy;
        feats[wave][lane * 7 + 2] = sz;
        feats[wave][lane * 7 + 3] = rx;
        feats[wave][lane * 7 + 4] = ry;
        feats[wave][lane * 7 + 5] = rz;
        feats[wave][lane * 7 + 6] = dist;
    }
    __syncthreads();
    {
        int j = lane & 31;
        int half = lane >> 5;
        int i0 = half * 105;
        float acc = 0.0f;
        for (int i = i0; i < i0 + 105; i++) acc += feats[wave][i] * B_ff[i * 32 + j];
        acc += __shfl_xor(acc, 32, 64);
        if (half == 0) {
            float ffv = 6.283185307179586f * acc;
            sc[wave][j] = sinf(ffv);
            sc[wave][j + 32] = cosf(ffv);
        }
    }
    __syncthreads();
    {
        int j = lane & 15;
        int h = lane >> 4;
        float acc = 0.0f;
        for (int i = 16 * h; i < 16 * h + 16; i++) acc += sc[wave][i] * mlp_W[i * 16 + j];
        acc += __shfl_xor(acc, 16, 64);
        acc += __shfl_xor(acc, 32, 64);
        if (h == 0) zl[wave][j] = acc;
    }
    __syncthreads();
    // ---- sparsemax, wave-parallel on lanes 0-15 (bit-identical to serial)
    {
        int l = lane & 15;
        float zv = zl[wave][l];
        int rank = 0;
        #pragma unroll
        for (int j = 0; j < 16; j++) {
            float zj = zl[wave][j];
            rank += (zj > zv || (zj == zv && j < l)) ? 1 : 0;
        }
        if (lane < 16) sZs[wave][rank] = zv;
        __builtin_amdgcn_wave_barrier();   // keep write before reads (same wave)
        float cs = 0.0f;
        #pragma unroll
        for (int p = 0; p < 16; p++) {
            float zp = sZs[wave][p];
            cs += (p <= l) ? zp : 0.0f;    // +0.0f padding: only feeds cmp / cs-1
        }
        float zsl = sZs[wave][l];
        bool flag = (lane < 16) && (1.0f + (float)(l + 1) * zsl > cs);
        unsigned long long ball = __ballot(flag);
        int cnt = (int)__popcll(ball & 0xFFFFull);
        if (lane < 16) sCs[wave][l] = cs;
        __builtin_amdgcn_wave_barrier();
        float tau = (sCs[wave][cnt - 1] - 1.0f) / (float)cnt;
        if (lane < 16) w[wave][l] = fmaxf(zv - tau, 0.0f);
    }
    __syncthreads();
    float* Pp = P + (size_t)bn_ * (KNN * TKR);
    for (int e = lane; e < KNN * TKR; e += 64) {
        int k = e / TKR, t = e - TKR * k;
        float acc = 0.0f;
        for (int i = 0; i < 16; i++) acc += w[wave][i] * permx[(i * KNN + k) * TKR + t];
        Pp[e] = acc;
    }
}

// ---------------------------------------------------------------------------
// 3a. agg (scalar, CIN=3 only)
// ---------------------------------------------------------------------------
template <int CIN>
__global__ __launch_bounds__(256) void agg_kernel(
    const float* __restrict__ ft, int ftst,
    const float* __restrict__ P, const int* __restrict__ idx,
    float* __restrict__ Z, int kpad) {
    __shared__ float sP[KNN * TKR];
    __shared__ float sNb[KNN * CIN];
    __shared__ int sIdx[KNN];
    int bn_ = blockIdx.x;
    int b = bn_ >> 10;
    int tid = threadIdx.x;
    if (tid < KNN) sIdx[tid] = idx[(size_t)bn_ * KNN + tid];
    for (int e = tid; e < KNN * TKR; e += 256) sP[e] = P[(size_t)bn_ * (KNN * TKR) + e];
    __syncthreads();
    for (int e = tid; e < KNN * CIN; e += 256) {
        int k = e / CIN, c = e - k * CIN;
        sNb[e] = ft[((size_t)(b << 10) + sIdx[k]) * ftst + c];
    }
    __syncthreads();
    float* zp = Z + (size_t)bn_ * kpad;
    const int KW = TKR * CIN;
    for (int e = tid; e < kpad; e += 256) {
        float v;
        if (e < KW) {
            int t = e / CIN, c = e - t * CIN;
            float acc = 0.0f;
            #pragma unroll
            for (int k = 0; k < KNN; k++) acc += sNb[k * CIN + c] * sP[k * TKR + t];
            v = acc;
        } else if (e < KW + CIN) {
            v = ft[(size_t)bn_ * ftst + (e - KW)];
        } else {
            v = 0.0f;
        }
        zp[e] = v;
    }
}

// ---------------------------------------------------------------------------
// 3b. agg vectorized f32 out (CIN=64, L2/L3)
// ---------------------------------------------------------------------------
template <int CIN>
__global__ __launch_bounds__(256) void agg_v_kernel(
    const float* __restrict__ ft, int ftst,
    const float* __restrict__ P, const int* __restrict__ idx,
    float* __restrict__ Z, int kpad) {
    __shared__ float sP[KNN * TKR];
    __shared__ float sNb[KNN * CIN];
    __shared__ int sIdx[KNN];
    constexpr int C4 = CIN / 4;
    int bn_ = blockIdx.x;
    int b = bn_ >> 10;
    int tid = threadIdx.x;
    if (tid < KNN) sIdx[tid] = idx[(size_t)bn_ * KNN + tid];
    for (int e = tid; e < KNN * TKR; e += 256) sP[e] = P[(size_t)bn_ * (KNN * TKR) + e];
    __syncthreads();
    for (int e = tid; e < KNN * C4; e += 256) {
        int k = e / C4, c4 = (e - k * C4) * 4;
        *(float4*)&sNb[k * CIN + c4] =
            *(const float4*)&ft[((size_t)(b << 10) + sIdx[k]) * ftst + c4];
    }
    __syncthreads();
    float* zp = Z + (size_t)bn_ * kpad;
    const int KW = TKR * CIN;
    for (int e = tid; e < (kpad >> 2); e += 256) {
        int c0 = e * 4;
        float4 v;
        if (c0 < KW) {
            int t = c0 / CIN, c4 = c0 - t * CIN;
            float4 a = make_float4(0.f, 0.f, 0.f, 0.f);
            #pragma unroll
            for (int k = 0; k < KNN; k++) {
                float p = sP[k * TKR + t];
                float4 nb = *(const float4*)&sNb[k * CIN + c4];
                a.x += nb.x * p; a.y += nb.y * p;
                a.z += nb.z * p; a.w += nb.w * p;
            }
            v = a;
        } else if (c0 < KW + CIN) {
            v = *(const float4*)&ft[(size_t)bn_ * ftst + (c0 - KW)];
        } else {
            v = make_float4(0.f, 0.f, 0.f, 0.f);
        }
        *(float4*)&zp[c0] = v;
    }
}

// ---------------------------------------------------------------------------
// 3c. agg_v_split4 (R22): 4 rows per block (1 per wave), compute identical
//     to the proven 1-row pattern (conflict-free LDS, same FMA order), output
//     staged in an LDS image then written with lane=(kc,row,half) so each
//     wave stores 8 FULL 64B lines (R21's 1-row version had 2x write
//     amplification: 16B chunks at 2KB stride). CIN=128, kpad=1280 fixed.
// ---------------------------------------------------------------------------
__global__ __launch_bounds__(256) void agg_v_split4_kernel(
    const float* __restrict__ ft, int ftst,
    const float* __restrict__ P, const int* __restrict__ idx,
    u16* __restrict__ ZH, u16* __restrict__ ZL) {
    __shared__ int   sIdx4[4][KNN];
    __shared__ float sP4[4][KNN * TKR + 2];
    __shared__ float sNb4[4][KNN * 128];
    __shared__ __align__(16) u16 oH[4][640];
    __shared__ __align__(16) u16 oL[4][640];
    int tid = threadIdx.x;
    int wave = tid >> 6, lane = tid & 63;
    int r0 = blockIdx.x << 2;
    int b = r0 >> 10;                  // 4 rows never straddle a batch (4 | 1024)
    const int KW = TKR * 128;          // 1152

    if (tid < 4 * KNN) {
        int row = tid / KNN, k = tid - row * KNN;
        sIdx4[row][k] = idx[(size_t)(r0 + row) * KNN + k];
    }
    for (int e = tid; e < 4 * KNN * TKR; e += 256) {
        int row = e / (KNN * TKR), i = e - row * (KNN * TKR);
        sP4[row][i] = P[(size_t)(r0 + row) * (KNN * TKR) + i];
    }
    __syncthreads();
    for (int e = tid; e < 4 * KNN * 32; e += 256) {
        int row = e / (KNN * 32), rem = e - row * (KNN * 32);
        int k = rem >> 5, c4 = (rem & 31) << 2;
        *(float4*)&sNb4[row][k * 128 + c4] =
            *(const float4*)&ft[((size_t)(b << 10) + sIdx4[row][k]) * ftst + c4];
    }
    __syncthreads();

    #pragma unroll
    for (int pass = 0; pass < 2; pass++) {
        int ebase = pass * 640;
        // compute: wave w owns row w; 160 quads per row this pass
        for (int q = lane; q < 160; q += 64) {
            int e0 = ebase + q * 4;
            float4 v;
            if (e0 < KW) {
                int t = e0 >> 7, c = e0 & 127;
                float4 a = make_float4(0.f, 0.f, 0.f, 0.f);
                #pragma unroll
                for (int k = 0; k < KNN; k++) {
                    float p = sP4[wave][k * TKR + t];
                    float4 nb = *(const float4*)&sNb4[wave][k * 128 + c];
                    a.x += nb.x * p; a.y += nb.y * p;
                    a.z += nb.z * p; a.w += nb.w * p;
                }
                v = a;
            } else if (e0 < KW + 128) {
                v = *(const float4*)&ft[(size_t)(r0 + wave) * ftst + (e0 - KW)];
            } else {
                v = make_float4(0.f, 0.f, 0.f, 0.f);
            }
            u16 h[4], l[4];
            split_bf16(v.x, h[0], l[0]);
            split_bf16(v.y, h[1], l[1]);
            split_bf16(v.z, h[2], l[2]);
            split_bf16(v.w, h[3], l[3]);
            uint2 hv, lv;
            hv.x = (unsigned)h[0] | ((unsigned)h[1] << 16);
            hv.y = (unsigned)h[2] | ((unsigned)h[3] << 16);
            lv.x = (unsigned)l[0] | ((unsigned)l[1] << 16);
            lv.y = (unsigned)l[2] | ((unsigned)l[3] << 16);
            *(uint2*)&oH[wave][q * 4] = hv;
            *(uint2*)&oL[wave][q * 4] = lv;
        }
        __syncthreads();
        // coalesced write phase: u -> (kpl, kc, row, half); each wave writes
        // 2 tiles x 4 kc x 64B full lines.
        for (int u = tid; u < 640; u += 256) {
            int kpl = u >> 5, s = u & 31;
            int kc = s >> 3, row = (s >> 1) & 3, half = s & 1;
            int eloc = kpl * 32 + kc * 8 + half * 4;
            uint2 hv = *(const uint2*)&oH[row][eloc];
            uint2 lv = *(const uint2*)&oL[row][eloc];
            size_t off = (size_t)((pass * 20 + kpl) * 128 + (r0 >> 7)) * 4096
                       + (size_t)(kc * 1024 + ((r0 & 127) + row) * 8 + half * 4);
            *(uint2*)&ZH[off] = hv;
            *(uint2*)&ZL[off] = lv;
        }
        __syncthreads();   // protect oH/oL reuse in next pass
    }
}

// ---------------------------------------------------------------------------
// 4. 64x64 GEMM, LDS double-buffered + reg prefetch (proven R7). L1-L3.
// ---------------------------------------------------------------------------
template <bool GELU, bool HASBIAS>
__global__ __launch_bounds__(256) void gemm_f32_64db(
    const float* __restrict__ A, int lda,
    const float* __restrict__ B, int ldb, int K,
    const float* __restrict__ bias,
    float* __restrict__ C, int ldc) {
    __shared__ float As[2][16][64];
    __shared__ float Bs[2][16][64];
    int tid = threadIdx.x;
    int tx = tid & 15, ty = tid >> 4;
    int m0 = blockIdx.y * 64, n0 = blockIdx.x * 64;
    float acc[4][4];
    #pragma unroll
    for (int i = 0; i < 4; i++)
        #pragma unroll
        for (int j = 0; j < 4; j++) acc[i][j] = 0.0f;

    int ar = tid >> 2, ac0 = (tid & 3) * 4;
    const float* aptr = A + (size_t)(m0 + ar) * lda + ac0;
    int br = tid >> 4, bc = (tid & 15) * 4;
    const float* bptr = B + (size_t)br * ldb + n0 + bc;

    float4 pa = *(const float4*)(aptr);
    float4 pb = *(const float4*)(bptr);
    As[0][ac0 + 0][ar] = pa.x; As[0][ac0 + 1][ar] = pa.y;
    As[0][ac0 + 2][ar] = pa.z; As[0][ac0 + 3][ar] = pa.w;
    *(float4*)&Bs[0][br][bc] = pb;
    __syncthreads();

    int nk = K >> 4;
    for (int t = 0; t < nk; t++) {
        int buf = t & 1;
        bool more = (t + 1) < nk;
        if (more) {
            int k0 = (t + 1) << 4;
            pa = *(const float4*)(aptr + k0);
            pb = *(const float4*)(bptr + (size_t)k0 * ldb);
        }
        #pragma unroll
        for (int kk = 0; kk < 16; kk++) {
            float av[4], bv[4];
            *(float4*)&av[0] = *(const float4*)&As[buf][kk][ty * 4];
            *(float4*)&bv[0] = *(const float4*)&Bs[buf][kk][tx * 4];
            #pragma unroll
            for (int i = 0; i < 4; i++)
                #pragma unroll
                for (int j = 0; j < 4; j++) acc[i][j] += av[i] * bv[j];
        }
        if (more) {
            int nb = 1 - buf;
            As[nb][ac0 + 0][ar] = pa.x; As[nb][ac0 + 1][ar] = pa.y;
            As[nb][ac0 + 2][ar] = pa.z; As[nb][ac0 + 3][ar] = pa.w;
            *(float4*)&Bs[nb][br][bc] = pb;
        }
        __syncthreads();
    }
    #pragma unroll
    for (int i = 0; i < 4; i++) {
        int r = m0 + ty * 4 + i;
        int c = n0 + tx * 4;
        float v[4];
        #pragma unroll
        for (int j = 0; j < 4; j++) {
            float t = acc[i][j];
            if (HASBIAS) t += bias[c + j];
            if (GELU) t = gelu_f(t);
            v[j] = t;
        }
        *(float4*)(C + (size_t)r * ldc + c) = *(float4*)v;
    }
}

// ---------------------------------------------------------------------------
// 5a. convert_split: y=0 (R22 remap): feat f32 -> featH/featL bf16 packed
//     with COALESCED writes (thread -> (tile, kc, rloc); consecutive lanes
//     write contiguous 16B). Reads become 32B @ 2KB stride from L3-resident
//     feat — cheap vs the amplified HBM RMW writes of the old mapping.
//     y=1: W5 [512][1024] f32 -> w5t{H,L} tile-packed (row=n), unchanged.
// ---------------------------------------------------------------------------
__global__ __launch_bounds__(256) void convert_split(
    const float* __restrict__ feat, u16* __restrict__ fH, u16* __restrict__ fL,
    const float* __restrict__ W5, u16* __restrict__ wH, u16* __restrict__ wL) {
    int t = blockIdx.x * 256 + threadIdx.x;
    if (blockIdx.y == 0) {
        int T = t >> 9, s = t & 511;           // T: (kp, row-panel) tile id
        int kc = s >> 7, rloc = s & 127;
        int kp = T >> 7, rp = T & 127;
        int row = (rp << 7) + rloc;
        int k0 = (kp << 5) + (kc << 3);
        const float* fp = &feat[(size_t)row * 512 + k0];
        float4 a = *(const float4*)fp;
        float4 b = *(const float4*)(fp + 4);
        float v[8] = {a.x, a.y, a.z, a.w, b.x, b.y, b.z, b.w};
        u16 h[8], l[8];
        #pragma unroll
        for (int i = 0; i < 8; i++) split_bf16(v[i], h[i], l[i]);
        uint4 hv, lv;
        hv.x = (unsigned)h[0] | ((unsigned)h[1] << 16);
        hv.y = (unsigned)h[2] | ((unsigned)h[3] << 16);
        hv.z = (unsigned)h[4] | ((unsigned)h[5] << 16);
        hv.w = (unsigned)h[6] | ((unsigned)h[7] << 16);
        lv.x = (unsigned)l[0] | ((unsigned)l[1] << 16);
        lv.y = (unsigned)l[2] | ((unsigned)l[3] << 16);
        lv.z = (unsigned)l[4] | ((unsigned)l[5] << 16);
        lv.w = (unsigned)l[6] | ((unsigned)l[7] << 16);
        size_t off = (size_t)T * 4096 + kc * 1024 + rloc * 8;
        *(uint4*)&fH[off] = hv;
        *(uint4*)&fL[off] = lv;
    } else {
        if (t >= 512 * 1024) return;
        int n = t >> 9, k = t & 511;
        u16 h, l;
        split_bf16(W5[(size_t)k * 1024 + n], h, l);
        size_t off = pack_off(n, k, 8);
        wH[off] = h; wL[off] = l;
    }
}

// ---------------------------------------------------------------------------
// 5b. Unified bf16x3 split MFMA GEMM (AhBh + AhBl + AlBh, fp32 accum).
//     R16: operands tile-packed in global (8KB per (k-panel, row-panel) tile
//     == LDS image) so each global_load_lds reads 1KB CONTIGUOUS.
//     dbuf LDS + 1 barrier/K-step + bijective XCD swizzle.
// ---------------------------------------------------------------------------
template <bool STATS, bool GELU, bool HASBIAS>
__global__ __launch_bounds__(256) void mfma_bf16x3(
    const u16* __restrict__ fH, const u16* __restrict__ fL,
    const u16* __restrict__ wH, const u16* __restrict__ wL,
    int K, const float* __restrict__ bias,
    float* __restrict__ C, int ldc,
    float* __restrict__ partS, float* __restrict__ partQ) {
    __shared__ __align__(16) u16 lds[2][16384];  // 2 x 32 KB: Ah|Al|Bh|Bl x 8 KB
    int tid = threadIdx.x;
    int lane = tid & 63, wave = tid >> 6;
    int wr = wave >> 1, wc = wave & 1;
    int kg = lane >> 4, r = lane & 15;

    // bijective chunked XCD swizzle (nwg % 8 == 0 for both call sites)
    int nwg = gridDim.x * gridDim.y;
    int hw = blockIdx.y * gridDim.x + blockIdx.x;
    int logical = (hw & 7) * (nwg >> 3) + (hw >> 3);
    int nb = logical % gridDim.x;
    int mb = logical / gridDim.x;
    int m0 = mb << 7, n0 = nb << 7;
    int nmp = gridDim.y;   // row-panels of A
    int nnp = gridDim.x;   // row-panels of B

    const u16* src = (wave == 0) ? fH : (wave == 1) ? fL
                   : (wave == 2) ? wH : wL;

    f32x4 acc[4][4];
    #pragma unroll
    for (int i = 0; i < 4; i++)
        #pragma unroll
        for (int j = 0; j < 4; j++) {
            acc[i][j][0] = 0.0f; acc[i][j][1] = 0.0f;
            acc[i][j][2] = 0.0f; acc[i][j][3] = 0.0f;
        }

#define STAGE_K(BUF, TT) {                                                     \
    size_t tb = ((size_t)((wave < 2) ? ((TT) * nmp + mb)                       \
                                     : ((TT) * nnp + nb)) << 12);              \
    _Pragma("unroll")                                                          \
    for (int iw = 0; iw < 8; iw++) {                                           \
        const u16* gp = src + tb + (size_t)(((iw << 6) + lane) << 3);          \
        __builtin_amdgcn_global_load_lds(                                      \
            (const __attribute__((address_space(1))) void*)gp,                 \
            (__attribute__((address_space(3))) void*)&lds[BUF][(wave << 12) + (iw << 9)], \
            16, 0, 0);                                                         \
    } }

    int nk = K >> 5;
    STAGE_K(0, 0);
    __syncthreads();  // drain prologue stage
    for (int t = 0; t < nk; t++) {
        // issue next tile's loads first: latency hides under this tile's MFMA
        if (t + 1 < nk) STAGE_K((t + 1) & 1, (t + 1));
        const u16* lb = lds[t & 1];
        u16x8 bh[4], bl[4];
        #pragma unroll
        for (int fj = 0; fj < 4; fj++) {
            int bcol = (wc << 6) + (fj << 4) + r;
            bh[fj] = *(const u16x8*)&lb[ 8192 + (((kg << 7) + bcol) << 3)];
            bl[fj] = *(const u16x8*)&lb[12288 + (((kg << 7) + bcol) << 3)];
        }
        #pragma unroll
        for (int fi = 0; fi < 4; fi++) {
            int arow = (wr << 6) + (fi << 4) + r;
            u16x8 ah = *(const u16x8*)&lb[       (((kg << 7) + arow) << 3)];
            u16x8 al = *(const u16x8*)&lb[4096 + (((kg << 7) + arow) << 3)];
            #pragma unroll
            for (int fj = 0; fj < 4; fj++) {
                asm volatile("v_mfma_f32_16x16x32_bf16 %0, %1, %2, %0"
                             : "+v"(acc[fi][fj]) : "v"(ah), "v"(bh[fj]));
                asm volatile("v_mfma_f32_16x16x32_bf16 %0, %1, %2, %0"
                             : "+v"(acc[fi][fj]) : "v"(ah), "v"(bl[fj]));
                asm volatile("v_mfma_f32_16x16x32_bf16 %0, %1, %2, %0"
                             : "+v"(acc[fi][fj]) : "v"(al), "v"(bh[fj]));
            }
        }
        // single barrier per K-step: drains vmcnt(0) (next tile staged) and
        // separates this tile's reads from the t+2 stage into the same buffer.
        __syncthreads();
    }
#undef STAGE_K

    // hazard guard: MFMA (inline asm, invisible to hazard recognizer) ->
    // first VALU read of acc.
    asm volatile("s_nop 15\n\ts_nop 15" ::: "memory");

    float bvv[4];
    if (HASBIAS) {
        #pragma unroll
        for (int fj = 0; fj < 4; fj++) bvv[fj] = bias[n0 + (wc << 6) + (fj << 4) + r];
    }

    // C write: D row = (lane>>4)*4 + reg, col = lane&15 (m89-verified)
    #pragma unroll
    for (int fi = 0; fi < 4; fi++)
        #pragma unroll
        for (int ri = 0; ri < 4; ri++) {
            int row = m0 + (wr << 6) + (fi << 4) + (kg << 2) + ri;
            float* cp = C + (size_t)row * ldc + n0 + (wc << 6) + r;
            #pragma unroll
            for (int fj = 0; fj < 4; fj++) {
                float v = acc[fi][fj][ri];
                if (HASBIAS) v += bvv[fj];
                if (GELU) v = gelu_f(v);
                cp[fj << 4] = v;
            }
        }

    if (STATS) {
        // BN column partials over this block's 128 rows (deterministic order)
        __syncthreads();
        float* sS = (float*)lds;        // [8][128]
        float* sQ = sS + 1024;          // [8][128]
        int slot = (wr << 2) + kg;
        #pragma unroll
        for (int fj = 0; fj < 4; fj++) {
            float s = 0.0f, q = 0.0f;
            #pragma unroll
            for (int fi = 0; fi < 4; fi++)
                #pragma unroll
                for (int ri = 0; ri < 4; ri++) {
                    float v = acc[fi][fj][ri];
                    s += v; q += v * v;
                }
            int cl = (wc << 6) + (fj << 4) + r;
            sS[slot * 128 + cl] = s;
            sQ[slot * 128 + cl] = q;
        }
        __syncthreads();
        if (tid < 128) {
            float S = 0.0f, Q = 0.0f;
            #pragma unroll
            for (int i = 0; i < 8; i++) { S += sS[i * 128 + tid]; Q += sQ[i * 128 + tid]; }
            partS[(size_t)mb * 1024 + n0 + tid] = S;
            partQ[(size_t)mb * 1024 + n0 + tid] = Q;
        }
    }
}

// ---------------------------------------------------------------------------
// 6. stats_reduce over 128 per-m-block partials (deterministic order)
// ---------------------------------------------------------------------------
__global__ __launch_bounds__(256) void stats_reduce(
    const float* __restrict__ partS, const float* __restrict__ partQ,
    const float* __restrict__ g, const float* __restrict__ be,
    float* __restrict__ scaleb, float* __restrict__ shiftb) {
    int e = blockIdx.x * 256 + threadIdx.x;
    if (e >= 1024) return;
    double s = 0.0, q = 0.0;
    for (int mb = 0; mb < 128; mb++) {
        s += (double)partS[(size_t)mb * 1024 + e];
        q += (double)partQ[(size_t)mb * 1024 + e];
    }
    double m = s * (1.0 / 16384.0);
    double v = q * (1.0 / 16384.0) - m * m;
    float sc = g[e] * (float)(1.0 / sqrt(v + 1e-5));
    scaleb[e] = sc;
    shiftb[e] = be[e] - (float)m * sc;
}

// ---------------------------------------------------------------------------
// 7a. pool_partial (R21): grid (chunk 16, g 4, b 16) = 1024 blocks, float4
//     loads (4 channels/thread).
// ---------------------------------------------------------------------------
__global__ __launch_bounds__(256) void pool_partial(
    const float* __restrict__ f5, const float* __restrict__ scaleb,
    const float* __restrict__ shiftb,
    float* __restrict__ partM, double* __restrict__ partSd) {
    int chunk = blockIdx.x, g = blockIdx.y, b = blockIdx.z;
    int tid = threadIdx.x;
    int lane = tid & 63, nlane = tid >> 6;
    int c0 = (g << 8) + lane * 4;
    float4 sc = *(const float4*)&scaleb[c0];
    float4 sh = *(const float4*)&shiftb[c0];
    float m0 = -FLT_BIG, m1 = -FLT_BIG, m2 = -FLT_BIG, m3 = -FLT_BIG;
    double s0 = 0.0, s1 = 0.0, s2 = 0.0, s3 = 0.0;
    int nend = (chunk + 1) << 6;
    for (int n = (chunk << 6) + nlane; n < nend; n += 4) {
        float4 v = *(const float4*)&f5[((size_t)(b << 10) + n) * 1024 + c0];
        float g0 = gelu_f(v.x * sc.x + sh.x);
        float g1 = gelu_f(v.y * sc.y + sh.y);
        float g2 = gelu_f(v.z * sc.z + sh.z);
        float g3 = gelu_f(v.w * sc.w + sh.w);
        m0 = fmaxf(m0, g0); m1 = fmaxf(m1, g1);
        m2 = fmaxf(m2, g2); m3 = fmaxf(m3, g3);
        s0 += (double)g0; s1 += (double)g1;
        s2 += (double)g2; s3 += (double)g3;
    }
    __shared__ float smax[4][256];
    __shared__ double ssum[4][256];
    *(float4*)&smax[nlane][lane * 4] = make_float4(m0, m1, m2, m3);
    ssum[nlane][lane * 4 + 0] = s0;
    ssum[nlane][lane * 4 + 1] = s1;
    ssum[nlane][lane * 4 + 2] = s2;
    ssum[nlane][lane * 4 + 3] = s3;
    __syncthreads();
    if (nlane == 0) {
        size_t base = ((size_t)((b * 4 + g) * 16 + chunk)) * 256 + lane * 4;
        #pragma unroll
        for (int j = 0; j < 4; j++) {
            float mm = smax[0][lane * 4 + j];
            double ss = ssum[0][lane * 4 + j];
            #pragma unroll
            for (int i = 1; i < 4; i++) {
                mm = fmaxf(mm, smax[i][lane * 4 + j]);
                ss += ssum[i][lane * 4 + j];
            }
            partM[base + j] = mm;
            partSd[base + j] = ss;
        }
    }
}

// ---------------------------------------------------------------------------
// 7b. pool_finish: combine 16 chunk-partials per channel (ascending order)
// ---------------------------------------------------------------------------
__global__ __launch_bounds__(256) void pool_finish(
    const float* __restrict__ partM, const double* __restrict__ partSd,
    float* __restrict__ h) {
    int b = blockIdx.x;
    int e0 = threadIdx.x * 4;
    int g = e0 >> 8, cl = e0 & 255;
    float mm[4] = {-FLT_BIG, -FLT_BIG, -FLT_BIG, -FLT_BIG};
    double ss[4] = {0.0, 0.0, 0.0, 0.0};
    for (int chunk = 0; chunk < 16; chunk++) {
        size_t base = ((size_t)((b * 4 + g) * 16 + chunk)) * 256 + cl;
        float4 pm = *(const float4*)&partM[base];
        mm[0] = fmaxf(mm[0], pm.x); mm[1] = fmaxf(mm[1], pm.y);
        mm[2] = fmaxf(mm[2], pm.z); mm[3] = fmaxf(mm[3], pm.w);
        ss[0] += partSd[base + 0]; ss[1] += partSd[base + 1];
        ss[2] += partSd[base + 2]; ss[3] += partSd[base + 3];
    }
    #pragma unroll
    for (int j = 0; j < 4; j++) {
        h[(size_t)b * 2048 + e0 + j] = mm[j];
        h[(size_t)b * 2048 + 1024 + e0 + j] = (float)(ss[j] * (1.0 / 1024.0));
    }
}

// ---------------------------------------------------------------------------
// 8. FC head: split-K fp64 partials; fused reduce+BN+gelu.
// ---------------------------------------------------------------------------
__global__ __launch_bounds__(256) void fc_split(
    const float* __restrict__ X, const float* __restrict__ W,
    double* __restrict__ part, int Bn, int In, int Out, int KC) {
    int tid = blockIdx.x * 256 + threadIdx.x;
    if (tid >= Bn * Out * KC) return;
    int chunk = tid / (Bn * Out);
    int r = tid - chunk * (Bn * Out);
    int b = r / Out, j = r - b * Out;
    int len = In / KC;
    int i0 = chunk * len;
    const float* x = X + (size_t)b * In + i0;
    const float* w = W + (size_t)i0 * Out + j;
    double acc = 0.0;
    for (int i = 0; i < len; i++) acc += (double)x[i] * (double)w[(size_t)i * Out];
    part[tid] = acc;
}

__global__ __launch_bounds__(256) void fc_bn_gelu(
    const double* __restrict__ part, const float* __restrict__ bias,
    const float* __restrict__ g, const float* __restrict__ be,
    float* __restrict__ Y, int Out, int KC) {
    int j = blockIdx.x * 256 + threadIdx.x;
    if (j >= Out) return;
    float r[BSZ];
    for (int b = 0; b < BSZ; b++) {
        double acc = bias ? (double)bias[j] : 0.0;
        for (int c = 0; c < KC; c++) acc += part[(size_t)c * (BSZ * Out) + b * Out + j];
        r[b] = (float)acc;
    }
    double m = 0.0;
    for (int b = 0; b < BSZ; b++) m += (double)r[b];
    m /= (double)BSZ;
    double v = 0.0;
    for (int b = 0; b < BSZ; b++) {
        double dd = (double)r[b] - m;
        v += dd * dd;
    }
    v /= (double)BSZ;
    float sc = g[j] * (float)(1.0 / sqrt(v + 1e-5));
    float sh = be[j] - (float)m * sc;
    for (int b = 0; b < BSZ; b++) Y[b * Out + j] = gelu_f(r[b] * sc + sh);
}

__global__ __launch_bounds__(256) void fc_reduce(
    const double* __restrict__ part, const float* __restrict__ bias,
    float* __restrict__ Y, int Bn, int Out, int KC) {
    int r = blockIdx.x * 256 + threadIdx.x;
    if (r >= Bn * Out) return;
    int j = r % Out;
    double acc = bias ? (double)bias[j] : 0.0;
    for (int c = 0; c < KC; c++) acc += part[(size_t)c * (Bn * Out) + r];
    Y[r] = (float)acc;
}

// ---------------------------------------------------------------------------
extern "C" void kernel_launch(void* const* d_in, const int* in_sizes, int n_in,
                              void* d_out, int out_size, void* d_ws, size_t ws_size,
                              hipStream_t stream) {
    const float* x     = (const float*)d_in[0];
    const float* B_ff  = (const float*)d_in[1];
    const float* mlp_W = (const float*)d_in[2];
    const float* permx = (const float*)d_in[3];
    const float* W1 = (const float*)d_in[4];
    const float* b1 = (const float*)d_in[5];
    const float* S1 = (const float*)d_in[6];
    const float* W2 = (const float*)d_in[7];
    const float* b2 = (const float*)d_in[8];
    const float* S2 = (const float*)d_in[9];
    const float* W3 = (const float*)d_in[10];
    const float* b3 = (const float*)d_in[11];
    const float* S3 = (const float*)d_in[12];
    const float* W4 = (const float*)d_in[13];
    const float* b4 = (const float*)d_in[14];
    const float* S4 = (const float*)d_in[15];
    const float* W5 = (const float*)d_in[16];
    const float* g5 = (const float*)d_in[17];
    const float* be5 = (const float*)d_in[18];
    const float* L1 = (const float*)d_in[19];
    const float* g6 = (const float*)d_in[20];
    const float* be6 = (const float*)d_in[21];
    const float* L2 = (const float*)d_in[22];
    const float* bL2 = (const float*)d_in[23];
    const float* g7 = (const float*)d_in[24];
    const float* be7 = (const float*)d_in[25];
    const float* L3 = (const float*)d_in[26];
    const float* bL3 = (const float*)d_in[27];
    float* outp = (float*)d_out;

    const int BN = BSZ * NPT;  // 16384

    // workspace (float units; 16B-aligned). Same liveness unions as R14-R21;
    // pool partials alias the dead featH region (dead after conv5 mfma).
    float* ws = (float*)d_ws;
    float* pts   = ws;                         // 49152   (dead after L1 agg)
    int*   idxb  = (int*)(ws + 49152);         // 491520  (dead after L4 agg)
    float* Pb    = ws + 540672;                // 4423680 (dead after L4 agg)
    float* feat  = Pb + 4423680;               // 8388608 (x1|x2|x3|x4, stride 512)
    float* Zbig  = feat + 8388608;             // 20971520
    u16*   ZH    = (u16*)Zbig;                 // 16384x1280 u16 packed
    u16*   ZL    = (u16*)(Zbig + 10485760);    // 16384x1280 u16 packed
    float* f5    = Zbig;                       // union: 16777216 (after L4 gemm)
    u16*   featH = (u16*)(Zbig + 16777216);    // 8388608 u16 packed (Zbig tail)
    float* poolM = Zbig + 16777216;            // 262144 f (featH region, dead)
    double* poolS = (double*)(Zbig + 16777216 + 262144); // 262144 doubles
    float* w4slot = Zbig + 20971520;           // 327680 f
    u16*   w4tH  = (u16*)w4slot;               // 327680 u16 packed
    u16*   w4tL  = w4tH + 327680;              // 327680 u16 packed
    float* scb   = w4slot + 327680;            // 1024
    float* shb   = scb + 1024;                 // 1024
    float* hb    = shb + 1024;                 // 32768
    float* y1    = hb + 32768;                 // 8192
    float* y2    = y1 + 8192;                  // 4096
    float* partC_S = y2 + 4096;                // 131072
    float* partC_Q = partC_S + 131072;         // 131072
    double* partF  = (double*)(partC_Q + 131072); // 131072 doubles
    float* wsend = (float*)(partF + 131072);
    // aliases into dead front region (valid once convert_split runs):
    u16* featL = (u16*)ws;                     // [0, 4194304) f
    u16* w5tH  = (u16*)(ws + 4194304);         // [4194304, 4456448) f
    u16* w5tL  = (u16*)(ws + 4456448);         // [4456448, 4718592) f  (< Pb end)
    float* wz1   = Zbig + 11010048;            // 2048   (dead by L4 agg)
    float* wz2   = wz1 + 2048;                 // 40960
    float* wz3   = wz2 + 40960;                // 81920  (ends 11134976)
    size_t need_bytes = (size_t)(wsend - ws) * sizeof(float);
    if (ws_size < need_bytes) return;

    // setup: transpose + wz1-3 f32 + packed w4t bf16-split in one dispatch
    prep_all<<<dim3(1280, 5), 256, 0, stream>>>(
        x, pts, W1, S1, wz1, W2, S2, wz2, W3, S3, wz3, W4, S4, w4tH, w4tL);

    // fused kNN + basis (R20: u32 butterfly max + ballot/ctz argmax)
    knn_basis_kernel<<<BN / 4, 256, 0, stream>>>(pts, B_ff, mlp_W, permx, idxb, Pb);

    // ---- layer 1: CIN=3, kpad=32, N=64 ----
    agg_kernel<3><<<BN, 256, 0, stream>>>(pts, 3, Pb, idxb, Zbig, 32);
    gemm_f32_64db<true, true><<<dim3(1, 256), 256, 0, stream>>>(
        Zbig, 32, wz1, 64, 32, b1, feat + 0, 512);
    // ---- layer 2: CIN=64, kpad=640, N=64 ----
    agg_v_kernel<64><<<BN, 256, 0, stream>>>(feat + 0, 512, Pb, idxb, Zbig, 640);
    gemm_f32_64db<true, true><<<dim3(1, 256), 256, 0, stream>>>(
        Zbig, 640, wz2, 64, 640, b2, feat + 64, 512);
    // ---- layer 3: CIN=64, kpad=640, N=128 ----
    agg_v_kernel<64><<<BN, 256, 0, stream>>>(feat + 64, 512, Pb, idxb, Zbig, 640);
    gemm_f32_64db<true, true><<<dim3(2, 256), 256, 0, stream>>>(
        Zbig, 640, wz3, 128, 640, b3, feat + 128, 512);
    // ---- layer 4: CIN=128 -> agg_v_split4 (R22: coalesced packed writes) ----
    agg_v_split4_kernel<<<BN / 4, 256, 0, stream>>>(feat + 128, 512, Pb, idxb, ZH, ZL);
    mfma_bf16x3<false, true, true><<<dim3(2, 128), 256, 0, stream>>>(
        ZH, ZL, w4tH, w4tL, 1280, b4, feat + 256, 512, nullptr, nullptr);

    // ---- conv5 via bf16x3 split MFMA + fused BN partials (packed) ----
    convert_split<<<dim3(4096, 2), 256, 0, stream>>>(feat, featH, featL, W5, w5tH, w5tL);
    mfma_bf16x3<true, false, false><<<dim3(8, 128), 256, 0, stream>>>(
        featH, featL, w5tH, w5tL, 512, nullptr, f5, 1024, partC_S, partC_Q);

    stats_reduce<<<4, 256, 0, stream>>>(partC_S, partC_Q, g5, be5, scb, shb);
    // ---- pool: partial (1024 blocks, float4) + finish ----
    pool_partial<<<dim3(16, 4, BSZ), 256, 0, stream>>>(f5, scb, shb, poolM, poolS);
    pool_finish<<<BSZ, 256, 0, stream>>>(poolM, poolS, hb);

    // ---- FC head ----
    fc_split<<<(BSZ * 512 * 16 + 255) / 256, 256, 0, stream>>>(hb, L1, partF, BSZ, 2048, 512, 16);
    fc_bn_gelu<<<2, 256, 0, stream>>>(partF, nullptr, g6, be6, y1, 512, 16);
    fc_split<<<(BSZ * 256 * 8 + 255) / 256, 256, 0, stream>>>(y1, L2, partF, BSZ, 512, 256, 8);
    fc_bn_gelu<<<1, 256, 0, stream>>>(partF, bL2, g7, be7, y2, 256, 8);
    fc_split<<<(BSZ * 40 * 4 + 255) / 256, 256, 0, stream>>>(y2, L3, partF, BSZ, 256, 40, 4);
    fc_reduce<<<(BSZ * 40 + 255) / 256, 256, 0, stream>>>(partF, bL3, outp, BSZ, 40, 4);
}

// Round 11
// 690.636 us; speedup vs baseline: 1.1420x; 1.1420x over previous
//
#include <hip/hip_runtime.h>
#include <hip/hip_bf16.h>
#include <cstddef>

#define BSZ 16
#define NPT 1024
#define KNN 30
#define TKR 9
#define FLT_BIG 3.402823466e+38f

typedef unsigned short u16;
typedef __attribute__((ext_vector_type(8))) u16 u16x8;
typedef __attribute__((ext_vector_type(4))) float f32x4;

__device__ __forceinline__ float gelu_f(float x) {
    return 0.5f * x * (1.0f + erff(x * 0.7071067811865476f));
}

__device__ __forceinline__ u16 bf16_rne(float a) {
    unsigned u = __float_as_uint(a);
    u += 0x7FFFu + ((u >> 16) & 1u);
    return (u16)(u >> 16);
}
__device__ __forceinline__ float bf16_tof(u16 h) {
    return __uint_as_float(((unsigned)h) << 16);
}
__device__ __forceinline__ void split_bf16(float a, u16& h, u16& l) {
    h = bf16_rne(a);
    float r = a - bf16_tof(h);
    l = bf16_rne(r);
}

// Packed MFMA operand layout (R16): element (row, k) of a [Rows][K] operand
// lives at u16 offset  T*4096 + kc*1024 + (row&127)*8 + (k&7),
// where T = (k>>5)*(Rows>>7) + (row>>7), kc = (k>>3)&3.
// Each (k-panel, row-panel) tile is a contiguous 8KB block == LDS image.
__device__ __forceinline__ size_t pack_off(int row, int k, int npanels_row) {
    return (size_t)((k >> 5) * npanels_row + (row >> 7)) * 4096
         + (size_t)(((k >> 3) & 3) * 1024 + (row & 127) * 8 + (k & 7));
}

// ---------------------------------------------------------------------------
// 1. prep_all: layer 0 = transpose x; layers 1..3 = WZ_l = [W;S;pad] (f32);
//    layer 4 = bf16 split weights w4t{H,L}, tile-packed (Rows=256, K=1280).
// ---------------------------------------------------------------------------
__global__ __launch_bounds__(256) void prep_all(
    const float* __restrict__ x, float* __restrict__ pts,
    const float* __restrict__ W1, const float* __restrict__ S1, float* __restrict__ wz1,
    const float* __restrict__ W2, const float* __restrict__ S2, float* __restrict__ wz2,
    const float* __restrict__ W3, const float* __restrict__ S3, float* __restrict__ wz3,
    const float* __restrict__ W4, const float* __restrict__ S4,
    u16* __restrict__ w4tH, u16* __restrict__ w4tL) {
    int layer = blockIdx.y;
    int t = blockIdx.x * 256 + threadIdx.x;
    if (layer == 0) {
        if (t >= BSZ * NPT) return;
        int b = t >> 10, n = t & 1023;
        const float* xp = x + (size_t)b * 3 * NPT;
        pts[t * 3 + 0] = xp[n];
        pts[t * 3 + 1] = xp[NPT + n];
        pts[t * 3 + 2] = xp[2 * NPT + n];
        return;
    }
    if (layer == 4) {
        // W4:[1152][256], S4:[128][256] -> packed w4t{H,L}, row=n in [0,256)
        if (t >= 1280 * 256) return;
        int k = t >> 8, n = t & 255;
        float v = (k < 1152) ? W4[(size_t)k * 256 + n] : S4[(size_t)(k - 1152) * 256 + n];
        u16 h, l;
        split_bf16(v, h, l);
        size_t off = pack_off(n, k, 2);
        w4tH[off] = h;
        w4tL[off] = l;
        return;
    }
    const float *W, *S; float* WZ; int KW, KS, N, kpad;
    if (layer == 1)      { W = W1; S = S1; WZ = wz1; KW = 27;   KS = 3;   N = 64;  kpad = 32;  }
    else if (layer == 2) { W = W2; S = S2; WZ = wz2; KW = 576;  KS = 64;  N = 64;  kpad = 640; }
    else                 { W = W3; S = S3; WZ = wz3; KW = 576;  KS = 64;  N = 128; kpad = 640; }
    if (t >= kpad * N) return;
    int k = t / N, n = t - k * N;
    float v = 0.0f;
    if (k < KW) v = W[(size_t)k * N + n];
    else if (k < KW + KS) v = S[(size_t)(k - KW) * N + n];
    WZ[t] = v;
}

// ---------------------------------------------------------------------------
// 2. FUSED kNN + basis. R20: selection via u32 shfl_xor butterfly max
//    + ballot/ctz argmax + one shfl j-broadcast. Tie semantics ==
//    reference top_k (value desc, lower index first).
// ---------------------------------------------------------------------------
__global__ __launch_bounds__(256) void knn_basis_kernel(
    const float* __restrict__ pts, const float* __restrict__ B_ff,
    const float* __restrict__ mlp_W, const float* __restrict__ permx,
    int* __restrict__ idx, float* __restrict__ P) {
    __shared__ float npt[4][KNN * 3];
    __shared__ float feats[4][7 * KNN];
    __shared__ float sc[4][64];
    __shared__ float zl[4][16];
    __shared__ float w[4][16];
    __shared__ float sZs[4][16];
    __shared__ float sCs[4][16];
    __shared__ int sIds[4][KNN];
    int tid = threadIdx.x;
    int wave = tid >> 6, lane = tid & 63;
    int bn_ = blockIdx.x * 4 + wave;
    int b = bn_ >> 10;

    // ---- kNN phase ----
    {
        double px = (double)pts[(size_t)bn_ * 3 + 0];
        double py = (double)pts[(size_t)bn_ * 3 + 1];
        double pz = (double)pts[(size_t)bn_ * 3 + 2];
        double xn = px * px + py * py + pz * pz;
        const float* pb = pts + (size_t)(b << 10) * 3;
        int base = lane * 16;
        unsigned mono[16];
        #pragma unroll
        for (int j = 0; j < 16; j++) {
            int m = base + j;
            double qx = (double)pb[m * 3 + 0];
            double qy = (double)pb[m * 3 + 1];
            double qz = (double)pb[m * 3 + 2];
            double inner = px * qx + py * qy + pz * qz;
            double xm = qx * qx + qy * qy + qz * qz;
            double cd = 2.0 * inner - xn - xm;          // exact ordering source
            float cf = (float)cd;                        // correctly-rounded f32
            unsigned bb = __float_as_uint(cf);
            mono[j] = (bb & 0x80000000u) ? ~bb : (bb | 0x80000000u);
        }
        unsigned alive = 0xFFFFu;
        unsigned c1v = 0u, c2v = 0u;
        int c1j = 0, c2j = 0;
        #pragma unroll
        for (int j = 0; j < 16; j++) {
            unsigned v = mono[j];
            if (v > c1v) { c2v = c1v; c2j = c1j; c1v = v; c1j = j; }
            else if (v > c2v) { c2v = v; c2j = j; }
        }
        bool have2 = true;
        for (int it = 0; it < KNN; it++) {
            unsigned m = c1v;
            #pragma unroll
            for (int s = 1; s < 64; s <<= 1) {
                unsigned ov = (unsigned)__shfl_xor((int)m, s, 64);
                m = (ov > m) ? ov : m;
            }
            unsigned long long ball = __ballot(c1v == m);
            int wlan = (int)__builtin_ctzll(ball);    // lowest lane = lowest idx
            int jw = __shfl(c1j, wlan, 64);
            int bi = (wlan << 4) + jw;
            if (lane == it) sIds[wave][it] = bi;
            if (lane == wlan) {
                alive &= ~(1u << c1j);
                if (have2) {
                    c1v = c2v; c1j = c2j; have2 = false;
                } else {
                    unsigned a1 = 0u, a2 = 0u;
                    int j1 = 0, j2 = 0;
                    #pragma unroll
                    for (int j = 0; j < 16; j++) {
                        unsigned v = ((alive >> j) & 1u) ? mono[j] : 0u;
                        if (v > a1) { a2 = a1; j2 = j1; a1 = v; j1 = j; }
                        else if (v > a2) { a2 = v; j2 = j; }
                    }
                    c1v = a1; c1j = j1; c2v = a2; c2j = j2;
                    have2 = true;
                }
            }
        }
        __builtin_amdgcn_wave_barrier();
        if (lane < KNN) idx[(size_t)bn_ * KNN + lane] = sIds[wave][lane];
    }
    __syncthreads();

    // ---- basis phase ----
    if (lane < KNN) {
        int m = sIds[wave][lane];
        const float* q = pts + ((size_t)(b << 10) + m) * 3;
        npt[wave][lane * 3 + 0] = q[0];
        npt[wave][lane * 3 + 1] = q[1];
        npt[wave][lane * 3 + 2] = q[2];
    }
    __syncthreads();
    if (lane < KNN) {
        float sx = npt[wave][0], sy = npt[wave][1], sz = npt[wave][2];
        float rx = npt[wave][lane * 3 + 0] - sx;
        float ry = npt[wave][lane * 3 + 1] - sy;
        float rz = npt[wave][lane * 3 + 2] - sz;
        float sq = rx * rx + ry * ry + rz * rz;
        float dist = (sq > 0.0f) ? sqrtf(sq) : 0.0f;
        feats[wave][lane * 7 + 0] = sx;
        feats[wave][lane * 7 + 1] = sy;
        feats[wave][lane * 7 + 2] = sz;
        feats[wave][lane * 7 + 3] = rx;
        feats[wave][lane * 7 + 4] = ry;
        feats[wave][lane * 7 + 5] = rz;
        feats[wave][lane * 7 + 6] = dist;
    }
    __syncthreads();
    {
        int j = lane & 31;
        int half = lane >> 5;
        int i0 = half * 105;
        float acc = 0.0f;
        for (int i = i0; i < i0 + 105; i++) acc += feats[wave][i] * B_ff[i * 32 + j];
        acc += __shfl_xor(acc, 32, 64);
        if (half == 0) {
            float ffv = 6.283185307179586f * acc;
            sc[wave][j] = sinf(ffv);
            sc[wave][j + 32] = cosf(ffv);
        }
    }
    __syncthreads();
    {
        int j = lane & 15;
        int h = lane >> 4;
        float acc = 0.0f;
        for (int i = 16 * h; i < 16 * h + 16; i++) acc += sc[wave][i] * mlp_W[i * 16 + j];
        acc += __shfl_xor(acc, 16, 64);
        acc += __shfl_xor(acc, 32, 64);
        if (h == 0) zl[wave][j] = acc;
    }
    __syncthreads();
    // ---- sparsemax, wave-parallel on lanes 0-15 (bit-identical to serial)
    {
        int l = lane & 15;
        float zv = zl[wave][l];
        int rank = 0;
        #pragma unroll
        for (int j = 0; j < 16; j++) {
            float zj = zl[wave][j];
            rank += (zj > zv || (zj == zv && j < l)) ? 1 : 0;
        }
        if (lane < 16) sZs[wave][rank] = zv;
        __builtin_amdgcn_wave_barrier();   // keep write before reads (same wave)
        float cs = 0.0f;
        #pragma unroll
        for (int p = 0; p < 16; p++) {
            float zp = sZs[wave][p];
            cs += (p <= l) ? zp : 0.0f;    // +0.0f padding: only feeds cmp / cs-1
        }
        float zsl = sZs[wave][l];
        bool flag = (lane < 16) && (1.0f + (float)(l + 1) * zsl > cs);
        unsigned long long ball = __ballot(flag);
        int cnt = (int)__popcll(ball & 0xFFFFull);
        if (lane < 16) sCs[wave][l] = cs;
        __builtin_amdgcn_wave_barrier();
        float tau = (sCs[wave][cnt - 1] - 1.0f) / (float)cnt;
        if (lane < 16) w[wave][l] = fmaxf(zv - tau, 0.0f);
    }
    __syncthreads();
    float* Pp = P + (size_t)bn_ * (KNN * TKR);
    for (int e = lane; e < KNN * TKR; e += 64) {
        int k = e / TKR, t = e - TKR * k;
        float acc = 0.0f;
        for (int i = 0; i < 16; i++) acc += w[wave][i] * permx[(i * KNN + k) * TKR + t];
        Pp[e] = acc;
    }
}

// ---------------------------------------------------------------------------
// 3a. agg (scalar, CIN=3 only)
// ---------------------------------------------------------------------------
template <int CIN>
__global__ __launch_bounds__(256) void agg_kernel(
    const float* __restrict__ ft, int ftst,
    const float* __restrict__ P, const int* __restrict__ idx,
    float* __restrict__ Z, int kpad) {
    __shared__ float sP[KNN * TKR];
    __shared__ float sNb[KNN * CIN];
    __shared__ int sIdx[KNN];
    int bn_ = blockIdx.x;
    int b = bn_ >> 10;
    int tid = threadIdx.x;
    if (tid < KNN) sIdx[tid] = idx[(size_t)bn_ * KNN + tid];
    for (int e = tid; e < KNN * TKR; e += 256) sP[e] = P[(size_t)bn_ * (KNN * TKR) + e];
    __syncthreads();
    for (int e = tid; e < KNN * CIN; e += 256) {
        int k = e / CIN, c = e - k * CIN;
        sNb[e] = ft[((size_t)(b << 10) + sIdx[k]) * ftst + c];
    }
    __syncthreads();
    float* zp = Z + (size_t)bn_ * kpad;
    const int KW = TKR * CIN;
    for (int e = tid; e < kpad; e += 256) {
        float v;
        if (e < KW) {
            int t = e / CIN, c = e - t * CIN;
            float acc = 0.0f;
            #pragma unroll
            for (int k = 0; k < KNN; k++) acc += sNb[k * CIN + c] * sP[k * TKR + t];
            v = acc;
        } else if (e < KW + CIN) {
            v = ft[(size_t)bn_ * ftst + (e - KW)];
        } else {
            v = 0.0f;
        }
        zp[e] = v;
    }
}

// ---------------------------------------------------------------------------
// 3b. agg vectorized f32 out (CIN=64, L2/L3)
// ---------------------------------------------------------------------------
template <int CIN>
__global__ __launch_bounds__(256) void agg_v_kernel(
    const float* __restrict__ ft, int ftst,
    const float* __restrict__ P, const int* __restrict__ idx,
    float* __restrict__ Z, int kpad) {
    __shared__ float sP[KNN * TKR];
    __shared__ float sNb[KNN * CIN];
    __shared__ int sIdx[KNN];
    constexpr int C4 = CIN / 4;
    int bn_ = blockIdx.x;
    int b = bn_ >> 10;
    int tid = threadIdx.x;
    if (tid < KNN) sIdx[tid] = idx[(size_t)bn_ * KNN + tid];
    for (int e = tid; e < KNN * TKR; e += 256) sP[e] = P[(size_t)bn_ * (KNN * TKR) + e];
    __syncthreads();
    for (int e = tid; e < KNN * C4; e += 256) {
        int k = e / C4, c4 = (e - k * C4) * 4;
        *(float4*)&sNb[k * CIN + c4] =
            *(const float4*)&ft[((size_t)(b << 10) + sIdx[k]) * ftst + c4];
    }
    __syncthreads();
    float* zp = Z + (size_t)bn_ * kpad;
    const int KW = TKR * CIN;
    for (int e = tid; e < (kpad >> 2); e += 256) {
        int c0 = e * 4;
        float4 v;
        if (c0 < KW) {
            int t = c0 / CIN, c4 = c0 - t * CIN;
            float4 a = make_float4(0.f, 0.f, 0.f, 0.f);
            #pragma unroll
            for (int k = 0; k < KNN; k++) {
                float p = sP[k * TKR + t];
                float4 nb = *(const float4*)&sNb[k * CIN + c4];
                a.x += nb.x * p; a.y += nb.y * p;
                a.z += nb.z * p; a.w += nb.w * p;
            }
            v = a;
        } else if (c0 < KW + CIN) {
            v = *(const float4*)&ft[(size_t)bn_ * ftst + (c0 - KW)];
        } else {
            v = make_float4(0.f, 0.f, 0.f, 0.f);
        }
        *(float4*)&zp[c0] = v;
    }
}

// ---------------------------------------------------------------------------
// 3c. agg_v_split8 (R23): 8 rows per block, NO neighbor LDS staging — each
//     thread owns a c-quad of one row and keeps 9 t-accumulators in REGISTERS
//     (neighbor float4 loaded once per k, reused 9x in-register; gather reads
//     stay coalesced 512B/row). Fixes R22's LDS-driven occupancy collapse
//     (76.8KB -> 2 blocks/CU, read BW halved). Output staged in padded LDS
//     images, then cooperative full-64B-line packed writes (R22's win kept).
//     FMA order per output: k ascending — bit-identical.
// ---------------------------------------------------------------------------
__global__ __launch_bounds__(256) void agg_v_split8_kernel(
    const float* __restrict__ ft, int ftst,
    const float* __restrict__ P, const int* __restrict__ idx,
    u16* __restrict__ ZH, u16* __restrict__ ZL) {
    __shared__ int   sIdx8[8][KNN];               // 960 B
    __shared__ float sP8[8][KNN * TKR];           // 8640 B
    __shared__ __align__(16) u16 oH[8][1288];     // padded +8: write-phase banks
    __shared__ __align__(16) u16 oL[8][1288];     // 2 x 20.6 KB
    int tid = threadIdx.x;
    int row = tid >> 5;            // 0..7
    int cq = tid & 31;             // c-quad
    int c0 = cq << 2;
    int r0 = blockIdx.x << 3;
    int b = r0 >> 10;              // 8 rows never straddle a batch (8 | 1024)

    if (tid < 8 * KNN) {
        int r = tid / KNN, k = tid - r * KNN;
        sIdx8[r][k] = idx[(size_t)(r0 + r) * KNN + k];
    }
    for (int e = tid; e < 8 * KNN * TKR; e += 256) {
        int r = e / (KNN * TKR), i = e - r * (KNN * TKR);
        sP8[r][i] = P[(size_t)(r0 + r) * (KNN * TKR) + i];
    }
    __syncthreads();

    float4 acc[9];
    #pragma unroll
    for (int t = 0; t < 9; t++) acc[t] = make_float4(0.f, 0.f, 0.f, 0.f);
    const float* fb = ft + (size_t)(b << 10) * ftst;
    for (int k = 0; k < KNN; k++) {
        float4 nb = *(const float4*)&fb[(size_t)sIdx8[row][k] * ftst + c0];
        #pragma unroll
        for (int t = 0; t < 9; t++) {
            float p = sP8[row][k * TKR + t];
            acc[t].x += nb.x * p; acc[t].y += nb.y * p;
            acc[t].z += nb.z * p; acc[t].w += nb.w * p;
        }
    }
    float4 self = *(const float4*)&ft[(size_t)(r0 + row) * ftst + c0];

    // stage splits into the LDS output image (e = t*128+c0; self at 1152+c0)
    #pragma unroll
    for (int t = 0; t < 10; t++) {
        float4 v = (t < 9) ? acc[t] : self;
        int e0 = (t < 9) ? (t * 128 + c0) : (1152 + c0);
        u16 h[4], l[4];
        split_bf16(v.x, h[0], l[0]);
        split_bf16(v.y, h[1], l[1]);
        split_bf16(v.z, h[2], l[2]);
        split_bf16(v.w, h[3], l[3]);
        uint2 hv, lv;
        hv.x = (unsigned)h[0] | ((unsigned)h[1] << 16);
        hv.y = (unsigned)h[2] | ((unsigned)h[3] << 16);
        lv.x = (unsigned)l[0] | ((unsigned)l[1] << 16);
        lv.y = (unsigned)l[2] | ((unsigned)l[3] << 16);
        *(uint2*)&oH[row][e0] = hv;
        *(uint2*)&oL[row][e0] = lv;
    }
    __syncthreads();

    // coalesced packed write: per k-panel, 8 lanes = one 64B line (4 rows).
    // u -> (kp, kc, rg, rw, half); lanes consecutive within 128B (kc chunk).
    for (int u = tid; u < 2560; u += 256) {
        int kp = u >> 6;
        int l = u & 63;
        int kc = l >> 4, rg = (l >> 3) & 1, rw = (l >> 1) & 3, half = l & 1;
        int rloc = rg * 4 + rw;
        int eloc = kp * 32 + kc * 8 + half * 4;
        uint2 hv = *(const uint2*)&oH[rloc][eloc];
        uint2 lv = *(const uint2*)&oL[rloc][eloc];
        size_t off = (size_t)(kp * 128 + (r0 >> 7)) * 4096
                   + (size_t)(kc * 1024 + ((r0 & 127) + rloc) * 8 + half * 4);
        *(uint2*)&ZH[off] = hv;
        *(uint2*)&ZL[off] = lv;
    }
}

// ---------------------------------------------------------------------------
// 4. 64x64 GEMM, LDS double-buffered + reg prefetch (proven R7). L1-L3.
// ---------------------------------------------------------------------------
template <bool GELU, bool HASBIAS>
__global__ __launch_bounds__(256) void gemm_f32_64db(
    const float* __restrict__ A, int lda,
    const float* __restrict__ B, int ldb, int K,
    const float* __restrict__ bias,
    float* __restrict__ C, int ldc) {
    __shared__ float As[2][16][64];
    __shared__ float Bs[2][16][64];
    int tid = threadIdx.x;
    int tx = tid & 15, ty = tid >> 4;
    int m0 = blockIdx.y * 64, n0 = blockIdx.x * 64;
    float acc[4][4];
    #pragma unroll
    for (int i = 0; i < 4; i++)
        #pragma unroll
        for (int j = 0; j < 4; j++) acc[i][j] = 0.0f;

    int ar = tid >> 2, ac0 = (tid & 3) * 4;
    const float* aptr = A + (size_t)(m0 + ar) * lda + ac0;
    int br = tid >> 4, bc = (tid & 15) * 4;
    const float* bptr = B + (size_t)br * ldb + n0 + bc;

    float4 pa = *(const float4*)(aptr);
    float4 pb = *(const float4*)(bptr);
    As[0][ac0 + 0][ar] = pa.x; As[0][ac0 + 1][ar] = pa.y;
    As[0][ac0 + 2][ar] = pa.z; As[0][ac0 + 3][ar] = pa.w;
    *(float4*)&Bs[0][br][bc] = pb;
    __syncthreads();

    int nk = K >> 4;
    for (int t = 0; t < nk; t++) {
        int buf = t & 1;
        bool more = (t + 1) < nk;
        if (more) {
            int k0 = (t + 1) << 4;
            pa = *(const float4*)(aptr + k0);
            pb = *(const float4*)(bptr + (size_t)k0 * ldb);
        }
        #pragma unroll
        for (int kk = 0; kk < 16; kk++) {
            float av[4], bv[4];
            *(float4*)&av[0] = *(const float4*)&As[buf][kk][ty * 4];
            *(float4*)&bv[0] = *(const float4*)&Bs[buf][kk][tx * 4];
            #pragma unroll
            for (int i = 0; i < 4; i++)
                #pragma unroll
                for (int j = 0; j < 4; j++) acc[i][j] += av[i] * bv[j];
        }
        if (more) {
            int nb = 1 - buf;
            As[nb][ac0 + 0][ar] = pa.x; As[nb][ac0 + 1][ar] = pa.y;
            As[nb][ac0 + 2][ar] = pa.z; As[nb][ac0 + 3][ar] = pa.w;
            *(float4*)&Bs[nb][br][bc] = pb;
        }
        __syncthreads();
    }
    #pragma unroll
    for (int i = 0; i < 4; i++) {
        int r = m0 + ty * 4 + i;
        int c = n0 + tx * 4;
        float v[4];
        #pragma unroll
        for (int j = 0; j < 4; j++) {
            float t = acc[i][j];
            if (HASBIAS) t += bias[c + j];
            if (GELU) t = gelu_f(t);
            v[j] = t;
        }
        *(float4*)(C + (size_t)r * ldc + c) = *(float4*)v;
    }
}

// ---------------------------------------------------------------------------
// 5a. convert_split: y=0 (R22 remap): feat f32 -> featH/featL bf16 packed
//     with COALESCED writes (thread -> (tile, kc, rloc); consecutive lanes
//     write contiguous 16B). y=1: W5 -> w5t{H,L} tile-packed (row=n).
// ---------------------------------------------------------------------------
__global__ __launch_bounds__(256) void convert_split(
    const float* __restrict__ feat, u16* __restrict__ fH, u16* __restrict__ fL,
    const float* __restrict__ W5, u16* __restrict__ wH, u16* __restrict__ wL) {
    int t = blockIdx.x * 256 + threadIdx.x;
    if (blockIdx.y == 0) {
        int T = t >> 9, s = t & 511;           // T: (kp, row-panel) tile id
        int kc = s >> 7, rloc = s & 127;
        int kp = T >> 7, rp = T & 127;
        int row = (rp << 7) + rloc;
        int k0 = (kp << 5) + (kc << 3);
        const float* fp = &feat[(size_t)row * 512 + k0];
        float4 a = *(const float4*)fp;
        float4 b = *(const float4*)(fp + 4);
        float v[8] = {a.x, a.y, a.z, a.w, b.x, b.y, b.z, b.w};
        u16 h[8], l[8];
        #pragma unroll
        for (int i = 0; i < 8; i++) split_bf16(v[i], h[i], l[i]);
        uint4 hv, lv;
        hv.x = (unsigned)h[0] | ((unsigned)h[1] << 16);
        hv.y = (unsigned)h[2] | ((unsigned)h[3] << 16);
        hv.z = (unsigned)h[4] | ((unsigned)h[5] << 16);
        hv.w = (unsigned)h[6] | ((unsigned)h[7] << 16);
        lv.x = (unsigned)l[0] | ((unsigned)l[1] << 16);
        lv.y = (unsigned)l[2] | ((unsigned)l[3] << 16);
        lv.z = (unsigned)l[4] | ((unsigned)l[5] << 16);
        lv.w = (unsigned)l[6] | ((unsigned)l[7] << 16);
        size_t off = (size_t)T * 4096 + kc * 1024 + rloc * 8;
        *(uint4*)&fH[off] = hv;
        *(uint4*)&fL[off] = lv;
    } else {
        if (t >= 512 * 1024) return;
        int n = t >> 9, k = t & 511;
        u16 h, l;
        split_bf16(W5[(size_t)k * 1024 + n], h, l);
        size_t off = pack_off(n, k, 8);
        wH[off] = h; wL[off] = l;
    }
}

// ---------------------------------------------------------------------------
// 5b. Unified bf16x3 split MFMA GEMM (AhBh + AhBl + AlBh, fp32 accum).
//     R16: operands tile-packed in global (8KB per (k-panel, row-panel) tile
//     == LDS image) so each global_load_lds reads 1KB CONTIGUOUS.
//     dbuf LDS + 1 barrier/K-step + bijective XCD swizzle.
// ---------------------------------------------------------------------------
template <bool STATS, bool GELU, bool HASBIAS>
__global__ __launch_bounds__(256) void mfma_bf16x3(
    const u16* __restrict__ fH, const u16* __restrict__ fL,
    const u16* __restrict__ wH, const u16* __restrict__ wL,
    int K, const float* __restrict__ bias,
    float* __restrict__ C, int ldc,
    float* __restrict__ partS, float* __restrict__ partQ) {
    __shared__ __align__(16) u16 lds[2][16384];  // 2 x 32 KB: Ah|Al|Bh|Bl x 8 KB
    int tid = threadIdx.x;
    int lane = tid & 63, wave = tid >> 6;
    int wr = wave >> 1, wc = wave & 1;
    int kg = lane >> 4, r = lane & 15;

    // bijective chunked XCD swizzle (nwg % 8 == 0 for both call sites)
    int nwg = gridDim.x * gridDim.y;
    int hw = blockIdx.y * gridDim.x + blockIdx.x;
    int logical = (hw & 7) * (nwg >> 3) + (hw >> 3);
    int nb = logical % gridDim.x;
    int mb = logical / gridDim.x;
    int m0 = mb << 7, n0 = nb << 7;
    int nmp = gridDim.y;   // row-panels of A
    int nnp = gridDim.x;   // row-panels of B

    const u16* src = (wave == 0) ? fH : (wave == 1) ? fL
                   : (wave == 2) ? wH : wL;

    f32x4 acc[4][4];
    #pragma unroll
    for (int i = 0; i < 4; i++)
        #pragma unroll
        for (int j = 0; j < 4; j++) {
            acc[i][j][0] = 0.0f; acc[i][j][1] = 0.0f;
            acc[i][j][2] = 0.0f; acc[i][j][3] = 0.0f;
        }

#define STAGE_K(BUF, TT) {                                                     \
    size_t tb = ((size_t)((wave < 2) ? ((TT) * nmp + mb)                       \
                                     : ((TT) * nnp + nb)) << 12);              \
    _Pragma("unroll")                                                          \
    for (int iw = 0; iw < 8; iw++) {                                           \
        const u16* gp = src + tb + (size_t)(((iw << 6) + lane) << 3);          \
        __builtin_amdgcn_global_load_lds(                                      \
            (const __attribute__((address_space(1))) void*)gp,                 \
            (__attribute__((address_space(3))) void*)&lds[BUF][(wave << 12) + (iw << 9)], \
            16, 0, 0);                                                         \
    } }

    int nk = K >> 5;
    STAGE_K(0, 0);
    __syncthreads();  // drain prologue stage
    for (int t = 0; t < nk; t++) {
        // issue next tile's loads first: latency hides under this tile's MFMA
        if (t + 1 < nk) STAGE_K((t + 1) & 1, (t + 1));
        const u16* lb = lds[t & 1];
        u16x8 bh[4], bl[4];
        #pragma unroll
        for (int fj = 0; fj < 4; fj++) {
            int bcol = (wc << 6) + (fj << 4) + r;
            bh[fj] = *(const u16x8*)&lb[ 8192 + (((kg << 7) + bcol) << 3)];
            bl[fj] = *(const u16x8*)&lb[12288 + (((kg << 7) + bcol) << 3)];
        }
        #pragma unroll
        for (int fi = 0; fi < 4; fi++) {
            int arow = (wr << 6) + (fi << 4) + r;
            u16x8 ah = *(const u16x8*)&lb[       (((kg << 7) + arow) << 3)];
            u16x8 al = *(const u16x8*)&lb[4096 + (((kg << 7) + arow) << 3)];
            #pragma unroll
            for (int fj = 0; fj < 4; fj++) {
                asm volatile("v_mfma_f32_16x16x32_bf16 %0, %1, %2, %0"
                             : "+v"(acc[fi][fj]) : "v"(ah), "v"(bh[fj]));
                asm volatile("v_mfma_f32_16x16x32_bf16 %0, %1, %2, %0"
                             : "+v"(acc[fi][fj]) : "v"(ah), "v"(bl[fj]));
                asm volatile("v_mfma_f32_16x16x32_bf16 %0, %1, %2, %0"
                             : "+v"(acc[fi][fj]) : "v"(al), "v"(bh[fj]));
            }
        }
        // single barrier per K-step: drains vmcnt(0) (next tile staged) and
        // separates this tile's reads from the t+2 stage into the same buffer.
        __syncthreads();
    }
#undef STAGE_K

    // hazard guard: MFMA (inline asm, invisible to hazard recognizer) ->
    // first VALU read of acc.
    asm volatile("s_nop 15\n\ts_nop 15" ::: "memory");

    float bvv[4];
    if (HASBIAS) {
        #pragma unroll
        for (int fj = 0; fj < 4; fj++) bvv[fj] = bias[n0 + (wc << 6) + (fj << 4) + r];
    }

    // C write: D row = (lane>>4)*4 + reg, col = lane&15 (m89-verified)
    #pragma unroll
    for (int fi = 0; fi < 4; fi++)
        #pragma unroll
        for (int ri = 0; ri < 4; ri++) {
            int row = m0 + (wr << 6) + (fi << 4) + (kg << 2) + ri;
            float* cp = C + (size_t)row * ldc + n0 + (wc << 6) + r;
            #pragma unroll
            for (int fj = 0; fj < 4; fj++) {
                float v = acc[fi][fj][ri];
                if (HASBIAS) v += bvv[fj];
                if (GELU) v = gelu_f(v);
                cp[fj << 4] = v;
            }
        }

    if (STATS) {
        // BN column partials over this block's 128 rows (deterministic order)
        __syncthreads();
        float* sS = (float*)lds;        // [8][128]
        float* sQ = sS + 1024;          // [8][128]
        int slot = (wr << 2) + kg;
        #pragma unroll
        for (int fj = 0; fj < 4; fj++) {
            float s = 0.0f, q = 0.0f;
            #pragma unroll
            for (int fi = 0; fi < 4; fi++)
                #pragma unroll
                for (int ri = 0; ri < 4; ri++) {
                    float v = acc[fi][fj][ri];
                    s += v; q += v * v;
                }
            int cl = (wc << 6) + (fj << 4) + r;
            sS[slot * 128 + cl] = s;
            sQ[slot * 128 + cl] = q;
        }
        __syncthreads();
        if (tid < 128) {
            float S = 0.0f, Q = 0.0f;
            #pragma unroll
            for (int i = 0; i < 8; i++) { S += sS[i * 128 + tid]; Q += sQ[i * 128 + tid]; }
            partS[(size_t)mb * 1024 + n0 + tid] = S;
            partQ[(size_t)mb * 1024 + n0 + tid] = Q;
        }
    }
}

// ---------------------------------------------------------------------------
// 6. stats_reduce over 128 per-m-block partials (deterministic order)
// ---------------------------------------------------------------------------
__global__ __launch_bounds__(256) void stats_reduce(
    const float* __restrict__ partS, const float* __restrict__ partQ,
    const float* __restrict__ g, const float* __restrict__ be,
    float* __restrict__ scaleb, float* __restrict__ shiftb) {
    int e = blockIdx.x * 256 + threadIdx.x;
    if (e >= 1024) return;
    double s = 0.0, q = 0.0;
    for (int mb = 0; mb < 128; mb++) {
        s += (double)partS[(size_t)mb * 1024 + e];
        q += (double)partQ[(size_t)mb * 1024 + e];
    }
    double m = s * (1.0 / 16384.0);
    double v = q * (1.0 / 16384.0) - m * m;
    float sc = g[e] * (float)(1.0 / sqrt(v + 1e-5));
    scaleb[e] = sc;
    shiftb[e] = be[e] - (float)m * sc;
}

// ---------------------------------------------------------------------------
// 7a. pool_partial (R21): grid (chunk 16, g 4, b 16) = 1024 blocks, float4
//     loads (4 channels/thread).
// ---------------------------------------------------------------------------
__global__ __launch_bounds__(256) void pool_partial(
    const float* __restrict__ f5, const float* __restrict__ scaleb,
    const float* __restrict__ shiftb,
    float* __restrict__ partM, double* __restrict__ partSd) {
    int chunk = blockIdx.x, g = blockIdx.y, b = blockIdx.z;
    int tid = threadIdx.x;
    int lane = tid & 63, nlane = tid >> 6;
    int c0 = (g << 8) + lane * 4;
    float4 sc = *(const float4*)&scaleb[c0];
    float4 sh = *(const float4*)&shiftb[c0];
    float m0 = -FLT_BIG, m1 = -FLT_BIG, m2 = -FLT_BIG, m3 = -FLT_BIG;
    double s0 = 0.0, s1 = 0.0, s2 = 0.0, s3 = 0.0;
    int nend = (chunk + 1) << 6;
    for (int n = (chunk << 6) + nlane; n < nend; n += 4) {
        float4 v = *(const float4*)&f5[((size_t)(b << 10) + n) * 1024 + c0];
        float g0 = gelu_f(v.x * sc.x + sh.x);
        float g1 = gelu_f(v.y * sc.y + sh.y);
        float g2 = gelu_f(v.z * sc.z + sh.z);
        float g3 = gelu_f(v.w * sc.w + sh.w);
        m0 = fmaxf(m0, g0); m1 = fmaxf(m1, g1);
        m2 = fmaxf(m2, g2); m3 = fmaxf(m3, g3);
        s0 += (double)g0; s1 += (double)g1;
        s2 += (double)g2; s3 += (double)g3;
    }
    __shared__ float smax[4][256];
    __shared__ double ssum[4][256];
    *(float4*)&smax[nlane][lane * 4] = make_float4(m0, m1, m2, m3);
    ssum[nlane][lane * 4 + 0] = s0;
    ssum[nlane][lane * 4 + 1] = s1;
    ssum[nlane][lane * 4 + 2] = s2;
    ssum[nlane][lane * 4 + 3] = s3;
    __syncthreads();
    if (nlane == 0) {
        size_t base = ((size_t)((b * 4 + g) * 16 + chunk)) * 256 + lane * 4;
        #pragma unroll
        for (int j = 0; j < 4; j++) {
            float mm = smax[0][lane * 4 + j];
            double ss = ssum[0][lane * 4 + j];
            #pragma unroll
            for (int i = 1; i < 4; i++) {
                mm = fmaxf(mm, smax[i][lane * 4 + j]);
                ss += ssum[i][lane * 4 + j];
            }
            partM[base + j] = mm;
            partSd[base + j] = ss;
        }
    }
}

// ---------------------------------------------------------------------------
// 7b. pool_finish: combine 16 chunk-partials per channel (ascending order)
// ---------------------------------------------------------------------------
__global__ __launch_bounds__(256) void pool_finish(
    const float* __restrict__ partM, const double* __restrict__ partSd,
    float* __restrict__ h) {
    int b = blockIdx.x;
    int e0 = threadIdx.x * 4;
    int g = e0 >> 8, cl = e0 & 255;
    float mm[4] = {-FLT_BIG, -FLT_BIG, -FLT_BIG, -FLT_BIG};
    double ss[4] = {0.0, 0.0, 0.0, 0.0};
    for (int chunk = 0; chunk < 16; chunk++) {
        size_t base = ((size_t)((b * 4 + g) * 16 + chunk)) * 256 + cl;
        float4 pm = *(const float4*)&partM[base];
        mm[0] = fmaxf(mm[0], pm.x); mm[1] = fmaxf(mm[1], pm.y);
        mm[2] = fmaxf(mm[2], pm.z); mm[3] = fmaxf(mm[3], pm.w);
        ss[0] += partSd[base + 0]; ss[1] += partSd[base + 1];
        ss[2] += partSd[base + 2]; ss[3] += partSd[base + 3];
    }
    #pragma unroll
    for (int j = 0; j < 4; j++) {
        h[(size_t)b * 2048 + e0 + j] = mm[j];
        h[(size_t)b * 2048 + 1024 + e0 + j] = (float)(ss[j] * (1.0 / 1024.0));
    }
}

// ---------------------------------------------------------------------------
// 8. FC head: split-K fp64 partials; fused reduce+BN+gelu.
// ---------------------------------------------------------------------------
__global__ __launch_bounds__(256) void fc_split(
    const float* __restrict__ X, const float* __restrict__ W,
    double* __restrict__ part, int Bn, int In, int Out, int KC) {
    int tid = blockIdx.x * 256 + threadIdx.x;
    if (tid >= Bn * Out * KC) return;
    int chunk = tid / (Bn * Out);
    int r = tid - chunk * (Bn * Out);
    int b = r / Out, j = r - b * Out;
    int len = In / KC;
    int i0 = chunk * len;
    const float* x = X + (size_t)b * In + i0;
    const float* w = W + (size_t)i0 * Out + j;
    double acc = 0.0;
    for (int i = 0; i < len; i++) acc += (double)x[i] * (double)w[(size_t)i * Out];
    part[tid] = acc;
}

__global__ __launch_bounds__(256) void fc_bn_gelu(
    const double* __restrict__ part, const float* __restrict__ bias,
    const float* __restrict__ g, const float* __restrict__ be,
    float* __restrict__ Y, int Out, int KC) {
    int j = blockIdx.x * 256 + threadIdx.x;
    if (j >= Out) return;
    float r[BSZ];
    for (int b = 0; b < BSZ; b++) {
        double acc = bias ? (double)bias[j] : 0.0;
        for (int c = 0; c < KC; c++) acc += part[(size_t)c * (BSZ * Out) + b * Out + j];
        r[b] = (float)acc;
    }
    double m = 0.0;
    for (int b = 0; b < BSZ; b++) m += (double)r[b];
    m /= (double)BSZ;
    double v = 0.0;
    for (int b = 0; b < BSZ; b++) {
        double dd = (double)r[b] - m;
        v += dd * dd;
    }
    v /= (double)BSZ;
    float sc = g[j] * (float)(1.0 / sqrt(v + 1e-5));
    float sh = be[j] - (float)m * sc;
    for (int b = 0; b < BSZ; b++) Y[b * Out + j] = gelu_f(r[b] * sc + sh);
}

__global__ __launch_bounds__(256) void fc_reduce(
    const double* __restrict__ part, const float* __restrict__ bias,
    float* __restrict__ Y, int Bn, int Out, int KC) {
    int r = blockIdx.x * 256 + threadIdx.x;
    if (r >= Bn * Out) return;
    int j = r % Out;
    double acc = bias ? (double)bias[j] : 0.0;
    for (int c = 0; c < KC; c++) acc += part[(size_t)c * (Bn * Out) + r];
    Y[r] = (float)acc;
}

// ---------------------------------------------------------------------------
extern "C" void kernel_launch(void* const* d_in, const int* in_sizes, int n_in,
                              void* d_out, int out_size, void* d_ws, size_t ws_size,
                              hipStream_t stream) {
    const float* x     = (const float*)d_in[0];
    const float* B_ff  = (const float*)d_in[1];
    const float* mlp_W = (const float*)d_in[2];
    const float* permx = (const float*)d_in[3];
    const float* W1 = (const float*)d_in[4];
    const float* b1 = (const float*)d_in[5];
    const float* S1 = (const float*)d_in[6];
    const float* W2 = (const float*)d_in[7];
    const float* b2 = (const float*)d_in[8];
    const float* S2 = (const float*)d_in[9];
    const float* W3 = (const float*)d_in[10];
    const float* b3 = (const float*)d_in[11];
    const float* S3 = (const float*)d_in[12];
    const float* W4 = (const float*)d_in[13];
    const float* b4 = (const float*)d_in[14];
    const float* S4 = (const float*)d_in[15];
    const float* W5 = (const float*)d_in[16];
    const float* g5 = (const float*)d_in[17];
    const float* be5 = (const float*)d_in[18];
    const float* L1 = (const float*)d_in[19];
    const float* g6 = (const float*)d_in[20];
    const float* be6 = (const float*)d_in[21];
    const float* L2 = (const float*)d_in[22];
    const float* bL2 = (const float*)d_in[23];
    const float* g7 = (const float*)d_in[24];
    const float* be7 = (const float*)d_in[25];
    const float* L3 = (const float*)d_in[26];
    const float* bL3 = (const float*)d_in[27];
    float* outp = (float*)d_out;

    const int BN = BSZ * NPT;  // 16384

    // workspace (float units; 16B-aligned). Same liveness unions as R14-R22;
    // pool partials alias the dead featH region (dead after conv5 mfma).
    float* ws = (float*)d_ws;
    float* pts   = ws;                         // 49152   (dead after L1 agg)
    int*   idxb  = (int*)(ws + 49152);         // 491520  (dead after L4 agg)
    float* Pb    = ws + 540672;                // 4423680 (dead after L4 agg)
    float* feat  = Pb + 4423680;               // 8388608 (x1|x2|x3|x4, stride 512)
    float* Zbig  = feat + 8388608;             // 20971520
    u16*   ZH    = (u16*)Zbig;                 // 16384x1280 u16 packed
    u16*   ZL    = (u16*)(Zbig + 10485760);    // 16384x1280 u16 packed
    float* f5    = Zbig;                       // union: 16777216 (after L4 gemm)
    u16*   featH = (u16*)(Zbig + 16777216);    // 8388608 u16 packed (Zbig tail)
    float* poolM = Zbig + 16777216;            // 262144 f (featH region, dead)
    double* poolS = (double*)(Zbig + 16777216 + 262144); // 262144 doubles
    float* w4slot = Zbig + 20971520;           // 327680 f
    u16*   w4tH  = (u16*)w4slot;               // 327680 u16 packed
    u16*   w4tL  = w4tH + 327680;              // 327680 u16 packed
    float* scb   = w4slot + 327680;            // 1024
    float* shb   = scb + 1024;                 // 1024
    float* hb    = shb + 1024;                 // 32768
    float* y1    = hb + 32768;                 // 8192
    float* y2    = y1 + 8192;                  // 4096
    float* partC_S = y2 + 4096;                // 131072
    float* partC_Q = partC_S + 131072;         // 131072
    double* partF  = (double*)(partC_Q + 131072); // 131072 doubles
    float* wsend = (float*)(partF + 131072);
    // aliases into dead front region (valid once convert_split runs):
    u16* featL = (u16*)ws;                     // [0, 4194304) f
    u16* w5tH  = (u16*)(ws + 4194304);         // [4194304, 4456448) f
    u16* w5tL  = (u16*)(ws + 4456448);         // [4456448, 4718592) f  (< Pb end)
    float* wz1   = Zbig + 11010048;            // 2048   (dead by L4 agg)
    float* wz2   = wz1 + 2048;                 // 40960
    float* wz3   = wz2 + 40960;                // 81920  (ends 11134976)
    size_t need_bytes = (size_t)(wsend - ws) * sizeof(float);
    if (ws_size < need_bytes) return;

    // setup: transpose + wz1-3 f32 + packed w4t bf16-split in one dispatch
    prep_all<<<dim3(1280, 5), 256, 0, stream>>>(
        x, pts, W1, S1, wz1, W2, S2, wz2, W3, S3, wz3, W4, S4, w4tH, w4tL);

    // fused kNN + basis (R20: u32 butterfly max + ballot/ctz argmax)
    knn_basis_kernel<<<BN / 4, 256, 0, stream>>>(pts, B_ff, mlp_W, permx, idxb, Pb);

    // ---- layer 1: CIN=3, kpad=32, N=64 ----
    agg_kernel<3><<<BN, 256, 0, stream>>>(pts, 3, Pb, idxb, Zbig, 32);
    gemm_f32_64db<true, true><<<dim3(1, 256), 256, 0, stream>>>(
        Zbig, 32, wz1, 64, 32, b1, feat + 0, 512);
    // ---- layer 2: CIN=64, kpad=640, N=64 ----
    agg_v_kernel<64><<<BN, 256, 0, stream>>>(feat + 0, 512, Pb, idxb, Zbig, 640);
    gemm_f32_64db<true, true><<<dim3(1, 256), 256, 0, stream>>>(
        Zbig, 640, wz2, 64, 640, b2, feat + 64, 512);
    // ---- layer 3: CIN=64, kpad=640, N=128 ----
    agg_v_kernel<64><<<BN, 256, 0, stream>>>(feat + 64, 512, Pb, idxb, Zbig, 640);
    gemm_f32_64db<true, true><<<dim3(2, 256), 256, 0, stream>>>(
        Zbig, 640, wz3, 128, 640, b3, feat + 128, 512);
    // ---- layer 4: CIN=128 -> agg_v_split8 (R23: reg accumulators, high occ,
    //      coalesced packed writes) ----
    agg_v_split8_kernel<<<BN / 8, 256, 0, stream>>>(feat + 128, 512, Pb, idxb, ZH, ZL);
    mfma_bf16x3<false, true, true><<<dim3(2, 128), 256, 0, stream>>>(
        ZH, ZL, w4tH, w4tL, 1280, b4, feat + 256, 512, nullptr, nullptr);

    // ---- conv5 via bf16x3 split MFMA + fused BN partials (packed) ----
    convert_split<<<dim3(4096, 2), 256, 0, stream>>>(feat, featH, featL, W5, w5tH, w5tL);
    mfma_bf16x3<true, false, false><<<dim3(8, 128), 256, 0, stream>>>(
        featH, featL, w5tH, w5tL, 512, nullptr, f5, 1024, partC_S, partC_Q);

    stats_reduce<<<4, 256, 0, stream>>>(partC_S, partC_Q, g5, be5, scb, shb);
    // ---- pool: partial (1024 blocks, float4) + finish ----
    pool_partial<<<dim3(16, 4, BSZ), 256, 0, stream>>>(f5, scb, shb, poolM, poolS);
    pool_finish<<<BSZ, 256, 0, stream>>>(poolM, poolS, hb);

    // ---- FC head ----
    fc_split<<<(BSZ * 512 * 16 + 255) / 256, 256, 0, stream>>>(hb, L1, partF, BSZ, 2048, 512, 16);
    fc_bn_gelu<<<2, 256, 0, stream>>>(partF, nullptr, g6, be6, y1, 512, 16);
    fc_split<<<(BSZ * 256 * 8 + 255) / 256, 256, 0, stream>>>(y1, L2, partF, BSZ, 512, 256, 8);
    fc_bn_gelu<<<1, 256, 0, stream>>>(partF, bL2, g7, be7, y2, 256, 8);
    fc_split<<<(BSZ * 40 * 4 + 255) / 256, 256, 0, stream>>>(y2, L3, partF, BSZ, 256, 40, 4);
    fc_reduce<<<(BSZ * 40 + 255) / 256, 256, 0, stream>>>(partF, bL3, outp, BSZ, 40, 4);
}

// Round 12
// 655.398 us; speedup vs baseline: 1.2034x; 1.0538x over previous
//
#include <hip/hip_runtime.h>
#include <hip/hip_bf16.h>
#include <cstddef>

#define BSZ 16
#define NPT 1024
#define KNN 30
#define TKR 9
#define FLT_BIG 3.402823466e+38f

typedef unsigned short u16;
typedef __attribute__((ext_vector_type(8))) u16 u16x8;
typedef __attribute__((ext_vector_type(4))) float f32x4;

__device__ __forceinline__ float gelu_f(float x) {
    return 0.5f * x * (1.0f + erff(x * 0.7071067811865476f));
}

__device__ __forceinline__ u16 bf16_rne(float a) {
    unsigned u = __float_as_uint(a);
    u += 0x7FFFu + ((u >> 16) & 1u);
    return (u16)(u >> 16);
}
__device__ __forceinline__ float bf16_tof(u16 h) {
    return __uint_as_float(((unsigned)h) << 16);
}
__device__ __forceinline__ void split_bf16(float a, u16& h, u16& l) {
    h = bf16_rne(a);
    float r = a - bf16_tof(h);
    l = bf16_rne(r);
}

// Packed MFMA operand layout (R16): element (row, k) of a [Rows][K] operand
// lives at u16 offset  T*4096 + kc*1024 + (row&127)*8 + (k&7),
// where T = (k>>5)*(Rows>>7) + (row>>7), kc = (k>>3)&3.
// Each (k-panel, row-panel) tile is a contiguous 8KB block == LDS image.
__device__ __forceinline__ size_t pack_off(int row, int k, int npanels_row) {
    return (size_t)((k >> 5) * npanels_row + (row >> 7)) * 4096
         + (size_t)(((k >> 3) & 3) * 1024 + (row & 127) * 8 + (k & 7));
}

// ---------------------------------------------------------------------------
// 1. prep_all: layer 0 = transpose x; layer 1 = wz1 f32 [32][64];
//    layers 2,3 (R24) = packed bf16 w{2,3}t{H,L} [128 rows][640] (L2 rows
//    64..127 zero-padded -> padded gemm cols = gelu(0)=0, overwritten later);
//    layer 4 = packed bf16 w4t{H,L} [256][1280].
// ---------------------------------------------------------------------------
__global__ __launch_bounds__(256) void prep_all(
    const float* __restrict__ x, float* __restrict__ pts,
    const float* __restrict__ W1, const float* __restrict__ S1, float* __restrict__ wz1,
    const float* __restrict__ W2, const float* __restrict__ S2,
    u16* __restrict__ w2tH, u16* __restrict__ w2tL,
    const float* __restrict__ W3, const float* __restrict__ S3,
    u16* __restrict__ w3tH, u16* __restrict__ w3tL,
    const float* __restrict__ W4, const float* __restrict__ S4,
    u16* __restrict__ w4tH, u16* __restrict__ w4tL) {
    int layer = blockIdx.y;
    int t = blockIdx.x * 256 + threadIdx.x;
    if (layer == 0) {
        if (t >= BSZ * NPT) return;
        int b = t >> 10, n = t & 1023;
        const float* xp = x + (size_t)b * 3 * NPT;
        pts[t * 3 + 0] = xp[n];
        pts[t * 3 + 1] = xp[NPT + n];
        pts[t * 3 + 2] = xp[2 * NPT + n];
        return;
    }
    if (layer == 1) {
        if (t >= 32 * 64) return;
        int k = t >> 6, n = t & 63;
        float v = 0.0f;
        if (k < 27) v = W1[(size_t)k * 64 + n];
        else if (k < 30) v = S1[(size_t)(k - 27) * 64 + n];
        wz1[t] = v;
        return;
    }
    if (layer == 2 || layer == 3) {
        if (t >= 640 * 128) return;
        int k = t >> 7, n = t & 127;          // k in [0,640), n in [0,128)
        const float* W = (layer == 2) ? W2 : W3;
        const float* S = (layer == 2) ? S2 : S3;
        int N = (layer == 2) ? 64 : 128;
        float v = 0.0f;
        if (n < N) v = (k < 576) ? W[(size_t)k * N + n] : S[(size_t)(k - 576) * N + n];
        u16 h, l;
        split_bf16(v, h, l);
        size_t off = pack_off(n, k, 1);
        if (layer == 2) { w2tH[off] = h; w2tL[off] = l; }
        else            { w3tH[off] = h; w3tL[off] = l; }
        return;
    }
    // layer 4: W4:[1152][256], S4:[128][256] -> packed w4t{H,L}
    if (t >= 1280 * 256) return;
    int k = t >> 8, n = t & 255;
    float v = (k < 1152) ? W4[(size_t)k * 256 + n] : S4[(size_t)(k - 1152) * 256 + n];
    u16 h, l;
    split_bf16(v, h, l);
    size_t off = pack_off(n, k, 2);
    w4tH[off] = h;
    w4tL[off] = l;
}

// ---------------------------------------------------------------------------
// 2. FUSED kNN + basis. R20: selection via u32 shfl_xor butterfly max
//    + ballot/ctz argmax + one shfl j-broadcast. Tie semantics ==
//    reference top_k (value desc, lower index first).
// ---------------------------------------------------------------------------
__global__ __launch_bounds__(256) void knn_basis_kernel(
    const float* __restrict__ pts, const float* __restrict__ B_ff,
    const float* __restrict__ mlp_W, const float* __restrict__ permx,
    int* __restrict__ idx, float* __restrict__ P) {
    __shared__ float npt[4][KNN * 3];
    __shared__ float feats[4][7 * KNN];
    __shared__ float sc[4][64];
    __shared__ float zl[4][16];
    __shared__ float w[4][16];
    __shared__ float sZs[4][16];
    __shared__ float sCs[4][16];
    __shared__ int sIds[4][KNN];
    int tid = threadIdx.x;
    int wave = tid >> 6, lane = tid & 63;
    int bn_ = blockIdx.x * 4 + wave;
    int b = bn_ >> 10;

    // ---- kNN phase ----
    {
        double px = (double)pts[(size_t)bn_ * 3 + 0];
        double py = (double)pts[(size_t)bn_ * 3 + 1];
        double pz = (double)pts[(size_t)bn_ * 3 + 2];
        double xn = px * px + py * py + pz * pz;
        const float* pb = pts + (size_t)(b << 10) * 3;
        int base = lane * 16;
        unsigned mono[16];
        #pragma unroll
        for (int j = 0; j < 16; j++) {
            int m = base + j;
            double qx = (double)pb[m * 3 + 0];
            double qy = (double)pb[m * 3 + 1];
            double qz = (double)pb[m * 3 + 2];
            double inner = px * qx + py * qy + pz * qz;
            double xm = qx * qx + qy * qy + qz * qz;
            double cd = 2.0 * inner - xn - xm;          // exact ordering source
            float cf = (float)cd;                        // correctly-rounded f32
            unsigned bb = __float_as_uint(cf);
            mono[j] = (bb & 0x80000000u) ? ~bb : (bb | 0x80000000u);
        }
        unsigned alive = 0xFFFFu;
        unsigned c1v = 0u, c2v = 0u;
        int c1j = 0, c2j = 0;
        #pragma unroll
        for (int j = 0; j < 16; j++) {
            unsigned v = mono[j];
            if (v > c1v) { c2v = c1v; c2j = c1j; c1v = v; c1j = j; }
            else if (v > c2v) { c2v = v; c2j = j; }
        }
        bool have2 = true;
        for (int it = 0; it < KNN; it++) {
            unsigned m = c1v;
            #pragma unroll
            for (int s = 1; s < 64; s <<= 1) {
                unsigned ov = (unsigned)__shfl_xor((int)m, s, 64);
                m = (ov > m) ? ov : m;
            }
            unsigned long long ball = __ballot(c1v == m);
            int wlan = (int)__builtin_ctzll(ball);    // lowest lane = lowest idx
            int jw = __shfl(c1j, wlan, 64);
            int bi = (wlan << 4) + jw;
            if (lane == it) sIds[wave][it] = bi;
            if (lane == wlan) {
                alive &= ~(1u << c1j);
                if (have2) {
                    c1v = c2v; c1j = c2j; have2 = false;
                } else {
                    unsigned a1 = 0u, a2 = 0u;
                    int j1 = 0, j2 = 0;
                    #pragma unroll
                    for (int j = 0; j < 16; j++) {
                        unsigned v = ((alive >> j) & 1u) ? mono[j] : 0u;
                        if (v > a1) { a2 = a1; j2 = j1; a1 = v; j1 = j; }
                        else if (v > a2) { a2 = v; j2 = j; }
                    }
                    c1v = a1; c1j = j1; c2v = a2; c2j = j2;
                    have2 = true;
                }
            }
        }
        __builtin_amdgcn_wave_barrier();
        if (lane < KNN) idx[(size_t)bn_ * KNN + lane] = sIds[wave][lane];
    }
    __syncthreads();

    // ---- basis phase ----
    if (lane < KNN) {
        int m = sIds[wave][lane];
        const float* q = pts + ((size_t)(b << 10) + m) * 3;
        npt[wave][lane * 3 + 0] = q[0];
        npt[wave][lane * 3 + 1] = q[1];
        npt[wave][lane * 3 + 2] = q[2];
    }
    __syncthreads();
    if (lane < KNN) {
        float sx = npt[wave][0], sy = npt[wave][1], sz = npt[wave][2];
        float rx = npt[wave][lane * 3 + 0] - sx;
        float ry = npt[wave][lane * 3 + 1] - sy;
        float rz = npt[wave][lane * 3 + 2] - sz;
        float sq = rx * rx + ry * ry + rz * rz;
        float dist = (sq > 0.0f) ? sqrtf(sq) : 0.0f;
        feats[wave][lane * 7 + 0] = sx;
        feats[wave][lane * 7 + 1] = sy;
        feats[wave][lane * 7 + 2] = sz;
        feats[wave][lane * 7 + 3] = rx;
        feats[wave][lane * 7 + 4] = ry;
        feats[wave][lane * 7 + 5] = rz;
        feats[wave][lane * 7 + 6] = dist;
    }
    __syncthreads();
    {
        int j = lane & 31;
        int half = lane >> 5;
        int i0 = half * 105;
        float acc = 0.0f;
        for (int i = i0; i < i0 + 105; i++) acc += feats[wave][i] * B_ff[i * 32 + j];
        acc += __shfl_xor(acc, 32, 64);
        if (half == 0) {
            float ffv = 6.283185307179586f * acc;
            sc[wave][j] = sinf(ffv);
            sc[wave][j + 32] = cosf(ffv);
        }
    }
    __syncthreads();
    {
        int j = lane & 15;
        int h = lane >> 4;
        float acc = 0.0f;
        for (int i = 16 * h; i < 16 * h + 16; i++) acc += sc[wave][i] * mlp_W[i * 16 + j];
        acc += __shfl_xor(acc, 16, 64);
        acc += __shfl_xor(acc, 32, 64);
        if (h == 0) zl[wave][j] = acc;
    }
    __syncthreads();
    // ---- sparsemax, wave-parallel on lanes 0-15 (bit-identical to serial)
    {
        int l = lane & 15;
        float zv = zl[wave][l];
        int rank = 0;
        #pragma unroll
        for (int j = 0; j < 16; j++) {
            float zj = zl[wave][j];
            rank += (zj > zv || (zj == zv && j < l)) ? 1 : 0;
        }
        if (lane < 16) sZs[wave][rank] = zv;
        __builtin_amdgcn_wave_barrier();   // keep write before reads (same wave)
        float cs = 0.0f;
        #pragma unroll
        for (int p = 0; p < 16; p++) {
            float zp = sZs[wave][p];
            cs += (p <= l) ? zp : 0.0f;    // +0.0f padding: only feeds cmp / cs-1
        }
        float zsl = sZs[wave][l];
        bool flag = (lane < 16) && (1.0f + (float)(l + 1) * zsl > cs);
        unsigned long long ball = __ballot(flag);
        int cnt = (int)__popcll(ball & 0xFFFFull);
        if (lane < 16) sCs[wave][l] = cs;
        __builtin_amdgcn_wave_barrier();
        float tau = (sCs[wave][cnt - 1] - 1.0f) / (float)cnt;
        if (lane < 16) w[wave][l] = fmaxf(zv - tau, 0.0f);
    }
    __syncthreads();
    float* Pp = P + (size_t)bn_ * (KNN * TKR);
    for (int e = lane; e < KNN * TKR; e += 64) {
        int k = e / TKR, t = e - TKR * k;
        float acc = 0.0f;
        for (int i = 0; i < 16; i++) acc += w[wave][i] * permx[(i * KNN + k) * TKR + t];
        Pp[e] = acc;
    }
}

// ---------------------------------------------------------------------------
// 3a. agg (scalar, CIN=3 only)
// ---------------------------------------------------------------------------
template <int CIN>
__global__ __launch_bounds__(256) void agg_kernel(
    const float* __restrict__ ft, int ftst,
    const float* __restrict__ P, const int* __restrict__ idx,
    float* __restrict__ Z, int kpad) {
    __shared__ float sP[KNN * TKR];
    __shared__ float sNb[KNN * CIN];
    __shared__ int sIdx[KNN];
    int bn_ = blockIdx.x;
    int b = bn_ >> 10;
    int tid = threadIdx.x;
    if (tid < KNN) sIdx[tid] = idx[(size_t)bn_ * KNN + tid];
    for (int e = tid; e < KNN * TKR; e += 256) sP[e] = P[(size_t)bn_ * (KNN * TKR) + e];
    __syncthreads();
    for (int e = tid; e < KNN * CIN; e += 256) {
        int k = e / CIN, c = e - k * CIN;
        sNb[e] = ft[((size_t)(b << 10) + sIdx[k]) * ftst + c];
    }
    __syncthreads();
    float* zp = Z + (size_t)bn_ * kpad;
    const int KW = TKR * CIN;
    for (int e = tid; e < kpad; e += 256) {
        float v;
        if (e < KW) {
            int t = e / CIN, c = e - t * CIN;
            float acc = 0.0f;
            #pragma unroll
            for (int k = 0; k < KNN; k++) acc += sNb[k * CIN + c] * sP[k * TKR + t];
            v = acc;
        } else if (e < KW + CIN) {
            v = ft[(size_t)bn_ * ftst + (e - KW)];
        } else {
            v = 0.0f;
        }
        zp[e] = v;
    }
}

// ---------------------------------------------------------------------------
// 3b. agg_v_split_c64 (R24): CIN=64 split-agg, 8 rows/block, c-PAIR per
//     thread (register accumulators, R23 structure; ~31 KB LDS -> 5
//     blocks/CU — avoids R22's occupancy collapse). Packed coalesced
//     writes (full 64B lines). kpad=640, K-panels=20. k-ascending FMA.
// ---------------------------------------------------------------------------
__global__ __launch_bounds__(256) void agg_v_split_c64_kernel(
    const float* __restrict__ ft, int ftst,
    const float* __restrict__ P, const int* __restrict__ idx,
    u16* __restrict__ ZH, u16* __restrict__ ZL) {
    __shared__ int   sIdx8[8][KNN];
    __shared__ float sP8[8][KNN * TKR];
    __shared__ __align__(16) u16 oH[8][644];
    __shared__ __align__(16) u16 oL[8][644];
    int tid = threadIdx.x;
    int row = tid >> 5, cp = tid & 31, c0 = cp << 1;
    int r0 = blockIdx.x << 3;
    int b = r0 >> 10;
    if (tid < 8 * KNN) {
        int r = tid / KNN, k = tid - r * KNN;
        sIdx8[r][k] = idx[(size_t)(r0 + r) * KNN + k];
    }
    for (int e = tid; e < 8 * KNN * TKR; e += 256) {
        int r = e / (KNN * TKR), i = e - r * (KNN * TKR);
        sP8[r][i] = P[(size_t)(r0 + r) * (KNN * TKR) + i];
    }
    __syncthreads();
    float2 acc[9];
    #pragma unroll
    for (int t = 0; t < 9; t++) acc[t] = make_float2(0.f, 0.f);
    const float* fb = ft + (size_t)(b << 10) * ftst;
    for (int k = 0; k < KNN; k++) {
        float2 nb = *(const float2*)&fb[(size_t)sIdx8[row][k] * ftst + c0];
        #pragma unroll
        for (int t = 0; t < 9; t++) {
            float p = sP8[row][k * TKR + t];
            acc[t].x += nb.x * p; acc[t].y += nb.y * p;
        }
    }
    float2 self = *(const float2*)&ft[(size_t)(r0 + row) * ftst + c0];
    #pragma unroll
    for (int t = 0; t < 10; t++) {
        float2 v = (t < 9) ? acc[t] : self;
        int e0 = (t < 9) ? (t * 64 + c0) : (576 + c0);
        u16 h0, l0, h1, l1;
        split_bf16(v.x, h0, l0);
        split_bf16(v.y, h1, l1);
        *(unsigned*)&oH[row][e0] = (unsigned)h0 | ((unsigned)h1 << 16);
        *(unsigned*)&oL[row][e0] = (unsigned)l0 | ((unsigned)l1 << 16);
    }
    __syncthreads();
    // packed write: 20 kp x (4 kc x 8 rloc x 2 half) = 1280 uint2
    for (int u = tid; u < 1280; u += 256) {
        int kp = u >> 6, s = u & 63;
        int kc = s >> 4, rloc = (s >> 1) & 7, half = s & 1;
        int eloc = kp * 32 + kc * 8 + half * 4;
        uint2 hv = *(const uint2*)&oH[rloc][eloc];
        uint2 lv = *(const uint2*)&oL[rloc][eloc];
        size_t off = (size_t)(kp * 128 + (r0 >> 7)) * 4096
                   + (size_t)(kc * 1024 + ((r0 & 127) + rloc) * 8 + half * 4);
        *(uint2*)&ZH[off] = hv;
        *(uint2*)&ZL[off] = lv;
    }
}

// ---------------------------------------------------------------------------
// 3c. agg_v_split8 (R23): CIN=128 split-agg, 8 rows/block, c-quad per
//     thread, register accumulators, packed coalesced writes. L4 producer.
// ---------------------------------------------------------------------------
__global__ __launch_bounds__(256) void agg_v_split8_kernel(
    const float* __restrict__ ft, int ftst,
    const float* __restrict__ P, const int* __restrict__ idx,
    u16* __restrict__ ZH, u16* __restrict__ ZL) {
    __shared__ int   sIdx8[8][KNN];
    __shared__ float sP8[8][KNN * TKR];
    __shared__ __align__(16) u16 oH[8][1288];
    __shared__ __align__(16) u16 oL[8][1288];
    int tid = threadIdx.x;
    int row = tid >> 5;
    int cq = tid & 31;
    int c0 = cq << 2;
    int r0 = blockIdx.x << 3;
    int b = r0 >> 10;

    if (tid < 8 * KNN) {
        int r = tid / KNN, k = tid - r * KNN;
        sIdx8[r][k] = idx[(size_t)(r0 + r) * KNN + k];
    }
    for (int e = tid; e < 8 * KNN * TKR; e += 256) {
        int r = e / (KNN * TKR), i = e - r * (KNN * TKR);
        sP8[r][i] = P[(size_t)(r0 + r) * (KNN * TKR) + i];
    }
    __syncthreads();

    float4 acc[9];
    #pragma unroll
    for (int t = 0; t < 9; t++) acc[t] = make_float4(0.f, 0.f, 0.f, 0.f);
    const float* fb = ft + (size_t)(b << 10) * ftst;
    for (int k = 0; k < KNN; k++) {
        float4 nb = *(const float4*)&fb[(size_t)sIdx8[row][k] * ftst + c0];
        #pragma unroll
        for (int t = 0; t < 9; t++) {
            float p = sP8[row][k * TKR + t];
            acc[t].x += nb.x * p; acc[t].y += nb.y * p;
            acc[t].z += nb.z * p; acc[t].w += nb.w * p;
        }
    }
    float4 self = *(const float4*)&ft[(size_t)(r0 + row) * ftst + c0];

    #pragma unroll
    for (int t = 0; t < 10; t++) {
        float4 v = (t < 9) ? acc[t] : self;
        int e0 = (t < 9) ? (t * 128 + c0) : (1152 + c0);
        u16 h[4], l[4];
        split_bf16(v.x, h[0], l[0]);
        split_bf16(v.y, h[1], l[1]);
        split_bf16(v.z, h[2], l[2]);
        split_bf16(v.w, h[3], l[3]);
        uint2 hv, lv;
        hv.x = (unsigned)h[0] | ((unsigned)h[1] << 16);
        hv.y = (unsigned)h[2] | ((unsigned)h[3] << 16);
        lv.x = (unsigned)l[0] | ((unsigned)l[1] << 16);
        lv.y = (unsigned)l[2] | ((unsigned)l[3] << 16);
        *(uint2*)&oH[row][e0] = hv;
        *(uint2*)&oL[row][e0] = lv;
    }
    __syncthreads();

    for (int u = tid; u < 2560; u += 256) {
        int kp = u >> 6;
        int l = u & 63;
        int kc = l >> 4, rg = (l >> 3) & 1, rw = (l >> 1) & 3, half = l & 1;
        int rloc = rg * 4 + rw;
        int eloc = kp * 32 + kc * 8 + half * 4;
        uint2 hv = *(const uint2*)&oH[rloc][eloc];
        uint2 lv = *(const uint2*)&oL[rloc][eloc];
        size_t off = (size_t)(kp * 128 + (r0 >> 7)) * 4096
                   + (size_t)(kc * 1024 + ((r0 & 127) + rloc) * 8 + half * 4);
        *(uint2*)&ZH[off] = hv;
        *(uint2*)&ZL[off] = lv;
    }
}

// ---------------------------------------------------------------------------
// 4. 64x64 GEMM, LDS double-buffered + reg prefetch (proven R7). L1 only.
// ---------------------------------------------------------------------------
template <bool GELU, bool HASBIAS>
__global__ __launch_bounds__(256) void gemm_f32_64db(
    const float* __restrict__ A, int lda,
    const float* __restrict__ B, int ldb, int K,
    const float* __restrict__ bias,
    float* __restrict__ C, int ldc) {
    __shared__ float As[2][16][64];
    __shared__ float Bs[2][16][64];
    int tid = threadIdx.x;
    int tx = tid & 15, ty = tid >> 4;
    int m0 = blockIdx.y * 64, n0 = blockIdx.x * 64;
    float acc[4][4];
    #pragma unroll
    for (int i = 0; i < 4; i++)
        #pragma unroll
        for (int j = 0; j < 4; j++) acc[i][j] = 0.0f;

    int ar = tid >> 2, ac0 = (tid & 3) * 4;
    const float* aptr = A + (size_t)(m0 + ar) * lda + ac0;
    int br = tid >> 4, bc = (tid & 15) * 4;
    const float* bptr = B + (size_t)br * ldb + n0 + bc;

    float4 pa = *(const float4*)(aptr);
    float4 pb = *(const float4*)(bptr);
    As[0][ac0 + 0][ar] = pa.x; As[0][ac0 + 1][ar] = pa.y;
    As[0][ac0 + 2][ar] = pa.z; As[0][ac0 + 3][ar] = pa.w;
    *(float4*)&Bs[0][br][bc] = pb;
    __syncthreads();

    int nk = K >> 4;
    for (int t = 0; t < nk; t++) {
        int buf = t & 1;
        bool more = (t + 1) < nk;
        if (more) {
            int k0 = (t + 1) << 4;
            pa = *(const float4*)(aptr + k0);
            pb = *(const float4*)(bptr + (size_t)k0 * ldb);
        }
        #pragma unroll
        for (int kk = 0; kk < 16; kk++) {
            float av[4], bv[4];
            *(float4*)&av[0] = *(const float4*)&As[buf][kk][ty * 4];
            *(float4*)&bv[0] = *(const float4*)&Bs[buf][kk][tx * 4];
            #pragma unroll
            for (int i = 0; i < 4; i++)
                #pragma unroll
                for (int j = 0; j < 4; j++) acc[i][j] += av[i] * bv[j];
        }
        if (more) {
            int nb = 1 - buf;
            As[nb][ac0 + 0][ar] = pa.x; As[nb][ac0 + 1][ar] = pa.y;
            As[nb][ac0 + 2][ar] = pa.z; As[nb][ac0 + 3][ar] = pa.w;
            *(float4*)&Bs[nb][br][bc] = pb;
        }
        __syncthreads();
    }
    #pragma unroll
    for (int i = 0; i < 4; i++) {
        int r = m0 + ty * 4 + i;
        int c = n0 + tx * 4;
        float v[4];
        #pragma unroll
        for (int j = 0; j < 4; j++) {
            float t = acc[i][j];
            if (HASBIAS) t += bias[c + j];
            if (GELU) t = gelu_f(t);
            v[j] = t;
        }
        *(float4*)(C + (size_t)r * ldc + c) = *(float4*)v;
    }
}

// ---------------------------------------------------------------------------
// 5a. convert_split: y=0 (R22 remap): feat f32 -> featH/featL bf16 packed
//     with coalesced writes. y=1: W5 -> w5t{H,L} tile-packed (row=n).
// ---------------------------------------------------------------------------
__global__ __launch_bounds__(256) void convert_split(
    const float* __restrict__ feat, u16* __restrict__ fH, u16* __restrict__ fL,
    const float* __restrict__ W5, u16* __restrict__ wH, u16* __restrict__ wL) {
    int t = blockIdx.x * 256 + threadIdx.x;
    if (blockIdx.y == 0) {
        int T = t >> 9, s = t & 511;           // T: (kp, row-panel) tile id
        int kc = s >> 7, rloc = s & 127;
        int kp = T >> 7, rp = T & 127;
        int row = (rp << 7) + rloc;
        int k0 = (kp << 5) + (kc << 3);
        const float* fp = &feat[(size_t)row * 512 + k0];
        float4 a = *(const float4*)fp;
        float4 b = *(const float4*)(fp + 4);
        float v[8] = {a.x, a.y, a.z, a.w, b.x, b.y, b.z, b.w};
        u16 h[8], l[8];
        #pragma unroll
        for (int i = 0; i < 8; i++) split_bf16(v[i], h[i], l[i]);
        uint4 hv, lv;
        hv.x = (unsigned)h[0] | ((unsigned)h[1] << 16);
        hv.y = (unsigned)h[2] | ((unsigned)h[3] << 16);
        hv.z = (unsigned)h[4] | ((unsigned)h[5] << 16);
        hv.w = (unsigned)h[6] | ((unsigned)h[7] << 16);
        lv.x = (unsigned)l[0] | ((unsigned)l[1] << 16);
        lv.y = (unsigned)l[2] | ((unsigned)l[3] << 16);
        lv.z = (unsigned)l[4] | ((unsigned)l[5] << 16);
        lv.w = (unsigned)l[6] | ((unsigned)l[7] << 16);
        size_t off = (size_t)T * 4096 + kc * 1024 + rloc * 8;
        *(uint4*)&fH[off] = hv;
        *(uint4*)&fL[off] = lv;
    } else {
        if (t >= 512 * 1024) return;
        int n = t >> 9, k = t & 511;
        u16 h, l;
        split_bf16(W5[(size_t)k * 1024 + n], h, l);
        size_t off = pack_off(n, k, 8);
        wH[off] = h; wL[off] = l;
    }
}

// ---------------------------------------------------------------------------
// 5b. Unified bf16x3 split MFMA GEMM (AhBh + AhBl + AlBh, fp32 accum).
//     Operands tile-packed (8KB tiles == LDS image -> contiguous 1KB
//     global_load_lds). dbuf LDS + 1 barrier/K-step + XCD swizzle.
//     R24: nbias guards padded-N bias reads (L2: N=64 padded to 128).
// ---------------------------------------------------------------------------
template <bool STATS, bool GELU, bool HASBIAS>
__global__ __launch_bounds__(256) void mfma_bf16x3(
    const u16* __restrict__ fH, const u16* __restrict__ fL,
    const u16* __restrict__ wH, const u16* __restrict__ wL,
    int K, const float* __restrict__ bias, int nbias,
    float* __restrict__ C, int ldc,
    float* __restrict__ partS, float* __restrict__ partQ) {
    __shared__ __align__(16) u16 lds[2][16384];  // 2 x 32 KB: Ah|Al|Bh|Bl x 8 KB
    int tid = threadIdx.x;
    int lane = tid & 63, wave = tid >> 6;
    int wr = wave >> 1, wc = wave & 1;
    int kg = lane >> 4, r = lane & 15;

    // bijective chunked XCD swizzle (nwg % 8 == 0 for all call sites)
    int nwg = gridDim.x * gridDim.y;
    int hw = blockIdx.y * gridDim.x + blockIdx.x;
    int logical = (hw & 7) * (nwg >> 3) + (hw >> 3);
    int nb = logical % gridDim.x;
    int mb = logical / gridDim.x;
    int m0 = mb << 7, n0 = nb << 7;
    int nmp = gridDim.y;   // row-panels of A
    int nnp = gridDim.x;   // row-panels of B

    const u16* src = (wave == 0) ? fH : (wave == 1) ? fL
                   : (wave == 2) ? wH : wL;

    f32x4 acc[4][4];
    #pragma unroll
    for (int i = 0; i < 4; i++)
        #pragma unroll
        for (int j = 0; j < 4; j++) {
            acc[i][j][0] = 0.0f; acc[i][j][1] = 0.0f;
            acc[i][j][2] = 0.0f; acc[i][j][3] = 0.0f;
        }

#define STAGE_K(BUF, TT) {                                                     \
    size_t tb = ((size_t)((wave < 2) ? ((TT) * nmp + mb)                       \
                                     : ((TT) * nnp + nb)) << 12);              \
    _Pragma("unroll")                                                          \
    for (int iw = 0; iw < 8; iw++) {                                           \
        const u16* gp = src + tb + (size_t)(((iw << 6) + lane) << 3);          \
        __builtin_amdgcn_global_load_lds(                                      \
            (const __attribute__((address_space(1))) void*)gp,                 \
            (__attribute__((address_space(3))) void*)&lds[BUF][(wave << 12) + (iw << 9)], \
            16, 0, 0);                                                         \
    } }

    int nk = K >> 5;
    STAGE_K(0, 0);
    __syncthreads();  // drain prologue stage
    for (int t = 0; t < nk; t++) {
        // issue next tile's loads first: latency hides under this tile's MFMA
        if (t + 1 < nk) STAGE_K((t + 1) & 1, (t + 1));
        const u16* lb = lds[t & 1];
        u16x8 bh[4], bl[4];
        #pragma unroll
        for (int fj = 0; fj < 4; fj++) {
            int bcol = (wc << 6) + (fj << 4) + r;
            bh[fj] = *(const u16x8*)&lb[ 8192 + (((kg << 7) + bcol) << 3)];
            bl[fj] = *(const u16x8*)&lb[12288 + (((kg << 7) + bcol) << 3)];
        }
        #pragma unroll
        for (int fi = 0; fi < 4; fi++) {
            int arow = (wr << 6) + (fi << 4) + r;
            u16x8 ah = *(const u16x8*)&lb[       (((kg << 7) + arow) << 3)];
            u16x8 al = *(const u16x8*)&lb[4096 + (((kg << 7) + arow) << 3)];
            #pragma unroll
            for (int fj = 0; fj < 4; fj++) {
                asm volatile("v_mfma_f32_16x16x32_bf16 %0, %1, %2, %0"
                             : "+v"(acc[fi][fj]) : "v"(ah), "v"(bh[fj]));
                asm volatile("v_mfma_f32_16x16x32_bf16 %0, %1, %2, %0"
                             : "+v"(acc[fi][fj]) : "v"(ah), "v"(bl[fj]));
                asm volatile("v_mfma_f32_16x16x32_bf16 %0, %1, %2, %0"
                             : "+v"(acc[fi][fj]) : "v"(al), "v"(bh[fj]));
            }
        }
        __syncthreads();
    }
#undef STAGE_K

    // hazard guard: MFMA (inline asm) -> first VALU read of acc.
    asm volatile("s_nop 15\n\ts_nop 15" ::: "memory");

    float bvv[4];
    if (HASBIAS) {
        #pragma unroll
        for (int fj = 0; fj < 4; fj++) {
            int col = n0 + (wc << 6) + (fj << 4) + r;
            bvv[fj] = (col < nbias) ? bias[col] : 0.0f;
        }
    }

    // C write: D row = (lane>>4)*4 + reg, col = lane&15 (m89-verified)
    #pragma unroll
    for (int fi = 0; fi < 4; fi++)
        #pragma unroll
        for (int ri = 0; ri < 4; ri++) {
            int row = m0 + (wr << 6) + (fi << 4) + (kg << 2) + ri;
            float* cp = C + (size_t)row * ldc + n0 + (wc << 6) + r;
            #pragma unroll
            for (int fj = 0; fj < 4; fj++) {
                float v = acc[fi][fj][ri];
                if (HASBIAS) v += bvv[fj];
                if (GELU) v = gelu_f(v);
                cp[fj << 4] = v;
            }
        }

    if (STATS) {
        __syncthreads();
        float* sS = (float*)lds;        // [8][128]
        float* sQ = sS + 1024;          // [8][128]
        int slot = (wr << 2) + kg;
        #pragma unroll
        for (int fj = 0; fj < 4; fj++) {
            float s = 0.0f, q = 0.0f;
            #pragma unroll
            for (int fi = 0; fi < 4; fi++)
                #pragma unroll
                for (int ri = 0; ri < 4; ri++) {
                    float v = acc[fi][fj][ri];
                    s += v; q += v * v;
                }
            int cl = (wc << 6) + (fj << 4) + r;
            sS[slot * 128 + cl] = s;
            sQ[slot * 128 + cl] = q;
        }
        __syncthreads();
        if (tid < 128) {
            float S = 0.0f, Q = 0.0f;
            #pragma unroll
            for (int i = 0; i < 8; i++) { S += sS[i * 128 + tid]; Q += sQ[i * 128 + tid]; }
            partS[(size_t)mb * 1024 + n0 + tid] = S;
            partQ[(size_t)mb * 1024 + n0 + tid] = Q;
        }
    }
}

// ---------------------------------------------------------------------------
// 6. stats_reduce over 128 per-m-block partials (deterministic order)
// ---------------------------------------------------------------------------
__global__ __launch_bounds__(256) void stats_reduce(
    const float* __restrict__ partS, const float* __restrict__ partQ,
    const float* __restrict__ g, const float* __restrict__ be,
    float* __restrict__ scaleb, float* __restrict__ shiftb) {
    int e = blockIdx.x * 256 + threadIdx.x;
    if (e >= 1024) return;
    double s = 0.0, q = 0.0;
    for (int mb = 0; mb < 128; mb++) {
        s += (double)partS[(size_t)mb * 1024 + e];
        q += (double)partQ[(size_t)mb * 1024 + e];
    }
    double m = s * (1.0 / 16384.0);
    double v = q * (1.0 / 16384.0) - m * m;
    float sc = g[e] * (float)(1.0 / sqrt(v + 1e-5));
    scaleb[e] = sc;
    shiftb[e] = be[e] - (float)m * sc;
}

// ---------------------------------------------------------------------------
// 7a. pool_partial (R21): grid (chunk 16, g 4, b 16) = 1024 blocks, float4
// ---------------------------------------------------------------------------
__global__ __launch_bounds__(256) void pool_partial(
    const float* __restrict__ f5, const float* __restrict__ scaleb,
    const float* __restrict__ shiftb,
    float* __restrict__ partM, double* __restrict__ partSd) {
    int chunk = blockIdx.x, g = blockIdx.y, b = blockIdx.z;
    int tid = threadIdx.x;
    int lane = tid & 63, nlane = tid >> 6;
    int c0 = (g << 8) + lane * 4;
    float4 sc = *(const float4*)&scaleb[c0];
    float4 sh = *(const float4*)&shiftb[c0];
    float m0 = -FLT_BIG, m1 = -FLT_BIG, m2 = -FLT_BIG, m3 = -FLT_BIG;
    double s0 = 0.0, s1 = 0.0, s2 = 0.0, s3 = 0.0;
    int nend = (chunk + 1) << 6;
    for (int n = (chunk << 6) + nlane; n < nend; n += 4) {
        float4 v = *(const float4*)&f5[((size_t)(b << 10) + n) * 1024 + c0];
        float g0 = gelu_f(v.x * sc.x + sh.x);
        float g1 = gelu_f(v.y * sc.y + sh.y);
        float g2 = gelu_f(v.z * sc.z + sh.z);
        float g3 = gelu_f(v.w * sc.w + sh.w);
        m0 = fmaxf(m0, g0); m1 = fmaxf(m1, g1);
        m2 = fmaxf(m2, g2); m3 = fmaxf(m3, g3);
        s0 += (double)g0; s1 += (double)g1;
        s2 += (double)g2; s3 += (double)g3;
    }
    __shared__ float smax[4][256];
    __shared__ double ssum[4][256];
    *(float4*)&smax[nlane][lane * 4] = make_float4(m0, m1, m2, m3);
    ssum[nlane][lane * 4 + 0] = s0;
    ssum[nlane][lane * 4 + 1] = s1;
    ssum[nlane][lane * 4 + 2] = s2;
    ssum[nlane][lane * 4 + 3] = s3;
    __syncthreads();
    if (nlane == 0) {
        size_t base = ((size_t)((b * 4 + g) * 16 + chunk)) * 256 + lane * 4;
        #pragma unroll
        for (int j = 0; j < 4; j++) {
            float mm = smax[0][lane * 4 + j];
            double ss = ssum[0][lane * 4 + j];
            #pragma unroll
            for (int i = 1; i < 4; i++) {
                mm = fmaxf(mm, smax[i][lane * 4 + j]);
                ss += ssum[i][lane * 4 + j];
            }
            partM[base + j] = mm;
            partSd[base + j] = ss;
        }
    }
}

// ---------------------------------------------------------------------------
// 7b. pool_finish: combine 16 chunk-partials per channel (ascending order)
// ---------------------------------------------------------------------------
__global__ __launch_bounds__(256) void pool_finish(
    const float* __restrict__ partM, const double* __restrict__ partSd,
    float* __restrict__ h) {
    int b = blockIdx.x;
    int e0 = threadIdx.x * 4;
    int g = e0 >> 8, cl = e0 & 255;
    float mm[4] = {-FLT_BIG, -FLT_BIG, -FLT_BIG, -FLT_BIG};
    double ss[4] = {0.0, 0.0, 0.0, 0.0};
    for (int chunk = 0; chunk < 16; chunk++) {
        size_t base = ((size_t)((b * 4 + g) * 16 + chunk)) * 256 + cl;
        float4 pm = *(const float4*)&partM[base];
        mm[0] = fmaxf(mm[0], pm.x); mm[1] = fmaxf(mm[1], pm.y);
        mm[2] = fmaxf(mm[2], pm.z); mm[3] = fmaxf(mm[3], pm.w);
        ss[0] += partSd[base + 0]; ss[1] += partSd[base + 1];
        ss[2] += partSd[base + 2]; ss[3] += partSd[base + 3];
    }
    #pragma unroll
    for (int j = 0; j < 4; j++) {
        h[(size_t)b * 2048 + e0 + j] = mm[j];
        h[(size_t)b * 2048 + 1024 + e0 + j] = (float)(ss[j] * (1.0 / 1024.0));
    }
}

// ---------------------------------------------------------------------------
// 8. FC head: split-K fp64 partials; fused reduce+BN+gelu.
// ---------------------------------------------------------------------------
__global__ __launch_bounds__(256) void fc_split(
    const float* __restrict__ X, const float* __restrict__ W,
    double* __restrict__ part, int Bn, int In, int Out, int KC) {
    int tid = blockIdx.x * 256 + threadIdx.x;
    if (tid >= Bn * Out * KC) return;
    int chunk = tid / (Bn * Out);
    int r = tid - chunk * (Bn * Out);
    int b = r / Out, j = r - b * Out;
    int len = In / KC;
    int i0 = chunk * len;
    const float* x = X + (size_t)b * In + i0;
    const float* w = W + (size_t)i0 * Out + j;
    double acc = 0.0;
    for (int i = 0; i < len; i++) acc += (double)x[i] * (double)w[(size_t)i * Out];
    part[tid] = acc;
}

__global__ __launch_bounds__(256) void fc_bn_gelu(
    const double* __restrict__ part, const float* __restrict__ bias,
    const float* __restrict__ g, const float* __restrict__ be,
    float* __restrict__ Y, int Out, int KC) {
    int j = blockIdx.x * 256 + threadIdx.x;
    if (j >= Out) return;
    float r[BSZ];
    for (int b = 0; b < BSZ; b++) {
        double acc = bias ? (double)bias[j] : 0.0;
        for (int c = 0; c < KC; c++) acc += part[(size_t)c * (BSZ * Out) + b * Out + j];
        r[b] = (float)acc;
    }
    double m = 0.0;
    for (int b = 0; b < BSZ; b++) m += (double)r[b];
    m /= (double)BSZ;
    double v = 0.0;
    for (int b = 0; b < BSZ; b++) {
        double dd = (double)r[b] - m;
        v += dd * dd;
    }
    v /= (double)BSZ;
    float sc = g[j] * (float)(1.0 / sqrt(v + 1e-5));
    float sh = be[j] - (float)m * sc;
    for (int b = 0; b < BSZ; b++) Y[b * Out + j] = gelu_f(r[b] * sc + sh);
}

__global__ __launch_bounds__(256) void fc_reduce(
    const double* __restrict__ part, const float* __restrict__ bias,
    float* __restrict__ Y, int Bn, int Out, int KC) {
    int r = blockIdx.x * 256 + threadIdx.x;
    if (r >= Bn * Out) return;
    int j = r % Out;
    double acc = bias ? (double)bias[j] : 0.0;
    for (int c = 0; c < KC; c++) acc += part[(size_t)c * (Bn * Out) + r];
    Y[r] = (float)acc;
}

// ---------------------------------------------------------------------------
extern "C" void kernel_launch(void* const* d_in, const int* in_sizes, int n_in,
                              void* d_out, int out_size, void* d_ws, size_t ws_size,
                              hipStream_t stream) {
    const float* x     = (const float*)d_in[0];
    const float* B_ff  = (const float*)d_in[1];
    const float* mlp_W = (const float*)d_in[2];
    const float* permx = (const float*)d_in[3];
    const float* W1 = (const float*)d_in[4];
    const float* b1 = (const float*)d_in[5];
    const float* S1 = (const float*)d_in[6];
    const float* W2 = (const float*)d_in[7];
    const float* b2 = (const float*)d_in[8];
    const float* S2 = (const float*)d_in[9];
    const float* W3 = (const float*)d_in[10];
    const float* b3 = (const float*)d_in[11];
    const float* S3 = (const float*)d_in[12];
    const float* W4 = (const float*)d_in[13];
    const float* b4 = (const float*)d_in[14];
    const float* S4 = (const float*)d_in[15];
    const float* W5 = (const float*)d_in[16];
    const float* g5 = (const float*)d_in[17];
    const float* be5 = (const float*)d_in[18];
    const float* L1 = (const float*)d_in[19];
    const float* g6 = (const float*)d_in[20];
    const float* be6 = (const float*)d_in[21];
    const float* L2 = (const float*)d_in[22];
    const float* bL2 = (const float*)d_in[23];
    const float* g7 = (const float*)d_in[24];
    const float* be7 = (const float*)d_in[25];
    const float* L3 = (const float*)d_in[26];
    const float* bL3 = (const float*)d_in[27];
    float* outp = (float*)d_out;

    const int BN = BSZ * NPT;  // 16384

    // workspace (float units; 16B-aligned). Liveness unions (R24):
    //   ZH/ZL slots serve L2/L3 (K=640: ZH fills [0,10485760) u16 exactly,
    //   ZL its own slot) then L4 (K=1280, full slots); L1's f32 Z uses the
    //   Zbig head before L2's ZH overwrites it; f5 aliases Zbig head after
    //   L4 mfma; featH = Zbig tail; pool partials alias dead featH; packed
    //   w2t/w3t + wz1 in a new dedicated tail (wz slots in Zbig are gone —
    //   they'd collide with ZL at K=640).
    float* ws = (float*)d_ws;
    float* pts   = ws;                         // 49152   (dead after L1 agg)
    int*   idxb  = (int*)(ws + 49152);         // 491520  (dead after L4 agg)
    float* Pb    = ws + 540672;                // 4423680 (dead after L4 agg)
    float* feat  = Pb + 4423680;               // 8388608 (x1|x2|x3|x4, stride 512)
    float* Zbig  = feat + 8388608;             // 20971520
    u16*   ZH    = (u16*)Zbig;                 // packed A-H (K<=1280)
    u16*   ZL    = (u16*)(Zbig + 10485760);    // packed A-L
    float* f5    = Zbig;                       // union: 16777216 (after L4 gemm)
    u16*   featH = (u16*)(Zbig + 16777216);    // 8388608 u16 packed (Zbig tail)
    float* poolM = Zbig + 16777216;            // 262144 f (featH region, dead)
    double* poolS = (double*)(Zbig + 16777216 + 262144); // 262144 doubles
    float* w4slot = Zbig + 20971520;           // 327680 f
    u16*   w4tH  = (u16*)w4slot;               // 327680 u16 packed
    u16*   w4tL  = w4tH + 327680;              // 327680 u16 packed
    float* scb   = w4slot + 327680;            // 1024
    float* shb   = scb + 1024;                 // 1024
    float* hb    = shb + 1024;                 // 32768
    float* y1    = hb + 32768;                 // 8192
    float* y2    = y1 + 8192;                  // 4096
    float* partC_S = y2 + 4096;                // 131072
    float* partC_Q = partC_S + 131072;         // 131072
    double* partF  = (double*)(partC_Q + 131072); // 131072 doubles
    // R24 tail: packed L2/L3 weights + wz1
    float* extra = (float*)(partF + 131072);
    u16* w2tH = (u16*)extra;                   // 81920 u16
    u16* w2tL = w2tH + 81920;                  // 81920 u16
    u16* w3tH = w2tL + 81920;                  // 81920 u16
    u16* w3tL = w3tH + 81920;                  // 81920 u16 (= 163840 f total)
    float* wz1 = extra + 163840;               // 2048 f
    float* wsend = wz1 + 2048;
    // aliases into dead front region (valid once convert_split runs):
    u16* featL = (u16*)ws;                     // [0, 4194304) f
    u16* w5tH  = (u16*)(ws + 4194304);         // [4194304, 4456448) f
    u16* w5tL  = (u16*)(ws + 4456448);         // [4456448, 4718592) f  (< Pb end)
    size_t need_bytes = (size_t)(wsend - ws) * sizeof(float);
    if (ws_size < need_bytes) return;

    // setup: transpose + wz1 f32 + packed w2t/w3t/w4t bf16-splits
    prep_all<<<dim3(1280, 5), 256, 0, stream>>>(
        x, pts, W1, S1, wz1, W2, S2, w2tH, w2tL, W3, S3, w3tH, w3tL,
        W4, S4, w4tH, w4tL);

    // fused kNN + basis (R20: u32 butterfly max + ballot/ctz argmax)
    knn_basis_kernel<<<BN / 4, 256, 0, stream>>>(pts, B_ff, mlp_W, permx, idxb, Pb);

    // ---- layer 1: CIN=3, kpad=32, N=64 (fp32, small) ----
    agg_kernel<3><<<BN, 256, 0, stream>>>(pts, 3, Pb, idxb, Zbig, 32);
    gemm_f32_64db<true, true><<<dim3(1, 256), 256, 0, stream>>>(
        Zbig, 32, wz1, 64, 32, b1, feat + 0, 512);
    // ---- layer 2: CIN=64, K=640, N=64 (padded to 128) -> bf16x3 MFMA ----
    agg_v_split_c64_kernel<<<BN / 8, 256, 0, stream>>>(feat + 0, 512, Pb, idxb, ZH, ZL);
    mfma_bf16x3<false, true, true><<<dim3(1, 128), 256, 0, stream>>>(
        ZH, ZL, w2tH, w2tL, 640, b2, 64, feat + 64, 512, nullptr, nullptr);
    // ---- layer 3: CIN=64, K=640, N=128 -> bf16x3 MFMA ----
    agg_v_split_c64_kernel<<<BN / 8, 256, 0, stream>>>(feat + 64, 512, Pb, idxb, ZH, ZL);
    mfma_bf16x3<false, true, true><<<dim3(1, 128), 256, 0, stream>>>(
        ZH, ZL, w3tH, w3tL, 640, b3, 128, feat + 128, 512, nullptr, nullptr);
    // ---- layer 4: CIN=128, K=1280, N=256 -> bf16x3 MFMA ----
    agg_v_split8_kernel<<<BN / 8, 256, 0, stream>>>(feat + 128, 512, Pb, idxb, ZH, ZL);
    mfma_bf16x3<false, true, true><<<dim3(2, 128), 256, 0, stream>>>(
        ZH, ZL, w4tH, w4tL, 1280, b4, 256, feat + 256, 512, nullptr, nullptr);

    // ---- conv5 via bf16x3 split MFMA + fused BN partials (packed) ----
    convert_split<<<dim3(4096, 2), 256, 0, stream>>>(feat, featH, featL, W5, w5tH, w5tL);
    mfma_bf16x3<true, false, false><<<dim3(8, 128), 256, 0, stream>>>(
        featH, featL, w5tH, w5tL, 512, nullptr, 0, f5, 1024, partC_S, partC_Q);

    stats_reduce<<<4, 256, 0, stream>>>(partC_S, partC_Q, g5, be5, scb, shb);
    // ---- pool: partial (1024 blocks, float4) + finish ----
    pool_partial<<<dim3(16, 4, BSZ), 256, 0, stream>>>(f5, scb, shb, poolM, poolS);
    pool_finish<<<BSZ, 256, 0, stream>>>(poolM, poolS, hb);

    // ---- FC head ----
    fc_split<<<(BSZ * 512 * 16 + 255) / 256, 256, 0, stream>>>(hb, L1, partF, BSZ, 2048, 512, 16);
    fc_bn_gelu<<<2, 256, 0, stream>>>(partF, nullptr, g6, be6, y1, 512, 16);
    fc_split<<<(BSZ * 256 * 8 + 255) / 256, 256, 0, stream>>>(y1, L2, partF, BSZ, 512, 256, 8);
    fc_bn_gelu<<<1, 256, 0, stream>>>(partF, bL2, g7, be7, y2, 256, 8);
    fc_split<<<(BSZ * 40 * 4 + 255) / 256, 256, 0, stream>>>(y2, L3, partF, BSZ, 256, 40, 4);
    fc_reduce<<<(BSZ * 40 + 255) / 256, 256, 0, stream>>>(partF, bL3, outp, BSZ, 40, 4);
}